// Round 10
// baseline (1315.434 us; speedup 1.0000x reference)
//
#include <hip/hip_runtime.h>
#include <hip/hip_bf16.h>
#include <math.h>

// ---------------- constants ----------------
constexpr int Bsz = 4, T = 2048, D = 512, H = 8, Lnum = 6, DFF = 2048, DK = 64;
constexpr int QS2 = 1024;                       // qkv row stride (q at 0, k at 512; v goes to vt)
constexpr float K2 = 0.08838834764831845f / 1.5f;  // softmax exponent scale (folded into q)

typedef __attribute__((ext_vector_type(8))) short svec8;   // 8 bf16 (4 VGPRs)
typedef __attribute__((ext_vector_type(4))) float fvec4;   // 4 fp32 acc

__device__ __forceinline__ fvec4 mfma16(svec8 a, svec8 b, fvec4 c) {
    return __builtin_amdgcn_mfma_f32_16x16x32_bf16(a, b, c, 0, 0, 0);
}
__device__ __forceinline__ unsigned short f2b(float f) {
    unsigned int u = __float_as_uint(f);
    u += 0x7fffu + ((u >> 16) & 1u);
    return (unsigned short)(u >> 16);
}
__device__ __forceinline__ unsigned int pk2b(float a, float b) {
    __hip_bfloat162 h = __float22bfloat162_rn(float2{a, b});
    return *(unsigned int*)&h;
}
__device__ __forceinline__ float wave_red_sum(float v) {
    for (int o = 32; o > 0; o >>= 1) v += __shfl_down(v, o, 64);
    return __shfl(v, 0, 64);
}
// async global->LDS, 16B per lane; lds base must be wave-uniform (HW adds lane*16)
__device__ __forceinline__ void glds16(const unsigned short* g, unsigned short* l) {
    __builtin_amdgcn_global_load_lds(
        (const __attribute__((address_space(1))) unsigned int*)g,
        (__attribute__((address_space(3))) unsigned int*)l, 16, 0, 0);
}
// s_waitcnt with vmcnt(n), lgkm/exp don't-care (n is compile-time 0..63)
#define WAITVM(n) __builtin_amdgcn_s_waitcnt(0x0F70 | ((n) & 0xF) | ((((n) >> 4) & 3) << 14))
// swizzled-tile fragment read: 64-wide rows, chunk kq of row r at slot kq^(r&7)
#define FRAG(buf, row, kq) (*(const svec8*)((buf) + (((row) << 6) | ((((kq) ^ ((row) & 7))) << 3))))

// ---------------- embed (fp32 h) ----------------
__global__ __launch_bounds__(64)
void embed_kernel(const float* __restrict__ x, const float* __restrict__ ip_w,
                  const float* __restrict__ ip_b, const float* __restrict__ g,
                  const float* __restrict__ bta, const float* __restrict__ pos,
                  const float* __restrict__ pad_tok, float* __restrict__ h)
{
    int row = blockIdx.x;
    int t = row & (T - 1);
    int lane = threadIdx.x;
    float xv = x[row];
    float xc = fminf(fmaxf(xv, -10.f), 10.f);
    bool pad = (xc == -1.0f);
    float pre[8];
    float s = 0.f, s2 = 0.f;
#pragma unroll
    for (int j = 0; j < 8; j++) {
        int d = j * 64 + lane;
        float p = xc * ip_w[d] + ip_b[d];
        pre[j] = p; s += p; s2 += p * p;
    }
    s = wave_red_sum(s); s2 = wave_red_sum(s2);
    float m = s * (1.f / 512.f);
    float var = s2 * (1.f / 512.f) - m * m;
    float rstd = 1.f / sqrtf(var + 1e-5f);
#pragma unroll
    for (int j = 0; j < 8; j++) {
        int d = j * 64 + lane;
        float hv = (pre[j] - m) * rstd * g[d] + bta[d] + 0.1f * pos[(size_t)t * D + d];
        if (pad) hv = pad_tok[d];
        h[(size_t)row * D + d] = hv;
    }
}

// ---------------- LayerNorm fp32 -> fp32 (final), 4 rows/block ----------------
__global__ __launch_bounds__(256)
void ln_kernel(const float* __restrict__ in, float* __restrict__ out,
               const float* __restrict__ g, const float* __restrict__ b)
{
    int row = blockIdx.x * 4 + (threadIdx.x >> 6);
    int lane = threadIdx.x & 63;
    const float* r = in + (size_t)row * D;
    float4 v0 = ((const float4*)r)[lane];
    float4 v1 = ((const float4*)r)[lane + 64];
    float s = v0.x + v0.y + v0.z + v0.w + v1.x + v1.y + v1.z + v1.w;
    float s2 = v0.x*v0.x + v0.y*v0.y + v0.z*v0.z + v0.w*v0.w
             + v1.x*v1.x + v1.y*v1.y + v1.z*v1.z + v1.w*v1.w;
    s = wave_red_sum(s); s2 = wave_red_sum(s2);
    float m = s * (1.f / 512.f);
    float var = s2 * (1.f / 512.f) - m * m;
    float rstd = 1.f / sqrtf(var + 1e-5f);
    float4 g0 = ((const float4*)g)[lane], g1 = ((const float4*)g)[lane + 64];
    float4 b0 = ((const float4*)b)[lane], b1 = ((const float4*)b)[lane + 64];
    float4 o0, o1;
    o0.x = (v0.x - m) * rstd * g0.x + b0.x; o0.y = (v0.y - m) * rstd * g0.y + b0.y;
    o0.z = (v0.z - m) * rstd * g0.z + b0.z; o0.w = (v0.w - m) * rstd * g0.w + b0.w;
    o1.x = (v1.x - m) * rstd * g1.x + b1.x; o1.y = (v1.y - m) * rstd * g1.y + b1.y;
    o1.z = (v1.z - m) * rstd * g1.z + b1.z; o1.w = (v1.w - m) * rstd * g1.w + b1.w;
    ((float4*)(out + (size_t)row * D))[lane] = o0;
    ((float4*)(out + (size_t)row * D))[lane + 64] = o1;
}

// ---------------- device LN fp32 -> bf16 helper (one wave, one row) ----------------
__device__ __forceinline__ void ln_row_bf16(const float* __restrict__ in, unsigned short* __restrict__ out,
                                            const float* __restrict__ g, const float* __restrict__ b,
                                            int row, int lane)
{
    const float* r = in + (size_t)row * D;
    float4 v0 = ((const float4*)r)[lane];
    float4 v1 = ((const float4*)r)[lane + 64];
    float s = v0.x + v0.y + v0.z + v0.w + v1.x + v1.y + v1.z + v1.w;
    float s2 = v0.x*v0.x + v0.y*v0.y + v0.z*v0.z + v0.w*v0.w
             + v1.x*v1.x + v1.y*v1.y + v1.z*v1.z + v1.w*v1.w;
    s = wave_red_sum(s); s2 = wave_red_sum(s2);
    float m = s * (1.f / 512.f);
    float var = s2 * (1.f / 512.f) - m * m;
    float rstd = 1.f / sqrtf(var + 1e-5f);
    float4 g0 = ((const float4*)g)[lane], g1 = ((const float4*)g)[lane + 64];
    float4 b0 = ((const float4*)b)[lane], b1 = ((const float4*)b)[lane + 64];
    unsigned short o0[4], o1[4];
    o0[0] = f2b((v0.x - m) * rstd * g0.x + b0.x); o0[1] = f2b((v0.y - m) * rstd * g0.y + b0.y);
    o0[2] = f2b((v0.z - m) * rstd * g0.z + b0.z); o0[3] = f2b((v0.w - m) * rstd * g0.w + b0.w);
    o1[0] = f2b((v1.x - m) * rstd * g1.x + b1.x); o1[1] = f2b((v1.y - m) * rstd * g1.y + b1.y);
    o1[2] = f2b((v1.z - m) * rstd * g1.z + b1.z); o1[3] = f2b((v1.w - m) * rstd * g1.w + b1.w);
    *(uint2*)(out + (size_t)row * D + lane * 4) = *(uint2*)o0;
    *(uint2*)(out + (size_t)row * D + 256 + lane * 4) = *(uint2*)o1;
}

__global__ __launch_bounds__(256)
void ln_bf16_kernel(const float* __restrict__ in, unsigned short* __restrict__ out,
                    const float* __restrict__ g, const float* __restrict__ b)
{
    ln_row_bf16(in, out, g, b, blockIdx.x * 4 + (threadIdx.x >> 6), threadIdx.x & 63);
}

// ---------------- fused per-layer prep: wconv (bid<3072) + ln1 (bid in [3072,5120)) ----------------
__global__ __launch_bounds__(256)
void prep_kernel(const float* __restrict__ wq, const float* __restrict__ wk,
                 const float* __restrict__ wv, const float* __restrict__ wo,
                 const float* __restrict__ w1, const float* __restrict__ w2,
                 unsigned short* __restrict__ oq, unsigned short* __restrict__ ok,
                 unsigned short* __restrict__ ov, unsigned short* __restrict__ oo,
                 unsigned short* __restrict__ o1, unsigned short* __restrict__ o2,
                 const float* __restrict__ hin, unsigned short* __restrict__ lnout,
                 const float* __restrict__ ln_g, const float* __restrict__ ln_b)
{
    __shared__ float tile[32][33];
    int bid = blockIdx.x;
    if (bid >= 3072) {
        int row = (bid - 3072) * 4 + (threadIdx.x >> 6);
        ln_row_bf16(hin, lnout, ln_g, ln_b, row, threadIdx.x & 63);
        return;
    }
    const float* in; unsigned short* out; int K, N, kt, nt;
    if (bid < 1024) {
        int sel = bid >> 8, loc = bid & 255;
        in  = sel == 0 ? wq : sel == 1 ? wk : sel == 2 ? wv : wo;
        out = sel == 0 ? oq : sel == 1 ? ok : sel == 2 ? ov : oo;
        K = 512; N = 512; kt = loc >> 4; nt = loc & 15;
    } else if (bid < 2048) {
        int loc = bid - 1024; in = w1; out = o1; K = 512; N = 2048; kt = loc >> 6; nt = loc & 63;
    } else {
        int loc = bid - 2048; in = w2; out = o2; K = 2048; N = 512; kt = loc >> 4; nt = loc & 15;
    }
    int k0 = kt * 32, n0 = nt * 32;
    int t = threadIdx.x;
    int kr = t >> 3, nc = (t & 7) * 4;
    float4 v = *(const float4*)(in + (size_t)(k0 + kr) * N + n0 + nc);
    tile[kr][nc] = v.x; tile[kr][nc + 1] = v.y; tile[kr][nc + 2] = v.z; tile[kr][nc + 3] = v.w;
    __syncthreads();
    unsigned short o[4];
#pragma unroll
    for (int i = 0; i < 4; i++) o[i] = f2b(tile[nc + i][kr]);
    *(uint2*)(out + (size_t)(n0 + kr) * K + k0 + nc) = *(uint2*)o;
}

// ---------------- bf16 MFMA GEMM, global_load_lds + BK=64 XOR swizzle ----------------
template<int EPI, int OBF, int BM>
__global__ __launch_bounds__(256)
void gemm_bf16(const unsigned short* __restrict__ A, const unsigned short* __restrict__ BT,
               const float* __restrict__ bias, const float* __restrict__ bias_b,
               const float* __restrict__ bias_c, const float* __restrict__ res,
               void* __restrict__ Cv, unsigned short* __restrict__ vtout,
               int M, int N, int K, const float* __restrict__ gate_p)
{
    constexpr int WN = (BM == 128) ? 2 : 4;
    constexpr int WSPAN = 128 / WN;
    constexpr int NT = WSPAN / 16;
    constexpr int MT = 4;
    constexpr int ACALLS = BM / 32;
    constexpr int SMEMSZ = (EPI == 0) ? 17408 : (BM * 64 + 128 * 64);
    __shared__ __align__(16) unsigned short SMEM[SMEMSZ];
    unsigned short* As = SMEM;
    unsigned short* Bs = SMEM + BM * 64;
    const int tid = threadIdx.x, w = tid >> 6, lane = tid & 63, quad = lane >> 4, ln = lane & 15;
    const int wm = w / WN, wn = w % WN;
    const int m0 = blockIdx.x * BM, n0 = blockIdx.y * 128;
    const int jg = (lane & 7) ^ ((lane >> 3) & 7);
    const int rb = w * 8 + (lane >> 3);
    const unsigned short* Agl = A + (size_t)(m0 + rb) * K + jg * 8;
    const unsigned short* Bgl = BT + (size_t)(n0 + rb) * K + jg * 8;

    fvec4 acc[MT][NT];
#pragma unroll
    for (int mt = 0; mt < MT; mt++)
#pragma unroll
        for (int nt = 0; nt < NT; nt++)
#pragma unroll
            for (int r = 0; r < 4; r++) acc[mt][nt][r] = 0.f;

    for (int k0 = 0; k0 < K; k0 += 64) {
        __syncthreads();
#pragma unroll
        for (int c = 0; c < ACALLS; c++)
            glds16(Agl + k0 + (size_t)c * 32 * K, As + c * 2048 + w * 512);
#pragma unroll
        for (int c = 0; c < 4; c++)
            glds16(Bgl + k0 + (size_t)c * 32 * K, Bs + c * 2048 + w * 512);
        __syncthreads();
#pragma unroll
        for (int kk = 0; kk < 2; kk++) {
            svec8 af[MT], bfr[NT];
#pragma unroll
            for (int mt = 0; mt < MT; mt++)
                af[mt] = FRAG(As, wm * 64 + mt * 16 + ln, kk * 4 + quad);
#pragma unroll
            for (int nt = 0; nt < NT; nt++)
                bfr[nt] = FRAG(Bs, wn * WSPAN + nt * 16 + ln, kk * 4 + quad);
#pragma unroll
            for (int mt = 0; mt < MT; mt++)
#pragma unroll
                for (int nt = 0; nt < NT; nt++)
                    acc[mt][nt] = mfma16(af[mt], bfr[nt], acc[mt][nt]);
        }
    }

    const float gate = (EPI == 1 || EPI == 3) ? gate_p[0] : 0.f;
    float bb[NT];
#pragma unroll
    for (int nt = 0; nt < NT; nt++) {
        int n = n0 + wn * WSPAN + nt * 16 + ln;
        if (EPI == 0) {
            int nseg = n >> 9;
            const float* bsel = nseg == 0 ? bias : (nseg == 1 ? bias_b : bias_c);
            bb[nt] = bsel[n - nseg * 512];
        } else {
            bb[nt] = bias[n];
        }
    }

    if (EPI == 0 && n0 >= 1024) {
        __syncthreads();
#pragma unroll
        for (int mt = 0; mt < MT; mt++) {
#pragma unroll
            for (int nt = 0; nt < NT; nt++) {
                int nl = wn * 64 + nt * 16 + ln;
                int mb = wm * 64 + mt * 16 + quad * 4;
                unsigned int lo = pk2b(acc[mt][nt][0] + bb[nt], acc[mt][nt][1] + bb[nt]);
                unsigned int hi = pk2b(acc[mt][nt][2] + bb[nt], acc[mt][nt][3] + bb[nt]);
                uint2 u; u.x = lo; u.y = hi;
                *(uint2*)(SMEM + nl * 136 + mb) = u;
            }
        }
        __syncthreads();
        int row = tid >> 1, half = (tid & 1) * 64;
        unsigned short* dst = vtout + ((size_t)((m0 >> 11) * 512 + (n0 - 1024) + row)) * T
                              + (m0 & (T - 1)) + half;
        const unsigned short* src = SMEM + row * 136 + half;
#pragma unroll
        for (int j = 0; j < 8; j++) *(uint4*)(dst + j * 8) = *(const uint4*)(src + j * 8);
        return;
    }

#pragma unroll
    for (int mt = 0; mt < MT; mt++) {
        float v[NT][4];
#pragma unroll
        for (int nt = 0; nt < NT; nt++)
#pragma unroll
            for (int r = 0; r < 4; r++) v[nt][r] = acc[mt][nt][r] + bb[nt];
        if (EPI == 0) {   // q/k: fused L2 norm; q additionally pre-scaled by K2
            const float fac = ((n0 + wn * WSPAN) < 512) ? K2 : 1.f;
#pragma unroll
            for (int r = 0; r < 4; r++) {
                float s = 0.f;
#pragma unroll
                for (int nt = 0; nt < NT; nt++) s += v[nt][r] * v[nt][r];
                s += __shfl_xor(s, 1); s += __shfl_xor(s, 2);
                s += __shfl_xor(s, 4); s += __shfl_xor(s, 8);
                float rs = fac / fmaxf(sqrtf(s), 1e-8f);
#pragma unroll
                for (int nt = 0; nt < NT; nt++) v[nt][r] *= rs;
            }
        }
#pragma unroll
        for (int nt = 0; nt < NT; nt++) {
            int n = n0 + wn * WSPAN + nt * 16 + ln;
#pragma unroll
            for (int r = 0; r < 4; r++) {
                int m = m0 + wm * 64 + mt * 16 + quad * 4 + r;
                float val = v[nt][r];
                if (EPI == 0) {
                    ((unsigned short*)Cv)[(size_t)m * QS2 + n] = f2b(val);
                } else {
                    size_t off = (size_t)m * N + n;
                    if (EPI == 1) val = res[off] + gate * 0.5f * val;
                    else if (EPI == 2) {
                        float u = val;
                        float z = 0.7978845608028654f * fmaf(0.044715f * u, u * u, u);
                        float e = __builtin_amdgcn_exp2f(z * 2.8853900817779268f);
                        float rr = __builtin_amdgcn_rcpf(e + 1.f);
                        val = u * (1.f - rr);
                    }
                    else if (EPI == 3) val = fminf(fmaxf(res[off] + gate * val, -10.f), 10.f);
                    if (OBF) ((unsigned short*)Cv)[off] = f2b(val);
                    else ((float*)Cv)[off] = val;
                }
            }
        }
    }
}

// ---------------- flash attention v2: 64q per wave, s-parity split, barrier-free K-loop ----------------
// One step: S^T = K.Q^T (Q in regs), softmax -> Ps (wave-private), O += P.V, l += P.1
template<bool DIAG>
__device__ __forceinline__ void attn_step64(
    unsigned short* Psw, const unsigned short* Ks, const unsigned short* Vt,
    const svec8 (&qf)[4][2], fvec4 (&oacc)[4][4], fvec4 (&lacc)[4],
    int quad, int ln)
{
    constexpr short BONE = (short)0x3F80;     // bf16 1.0
    const svec8 ONES8 = {BONE, BONE, BONE, BONE, BONE, BONE, BONE, BONE};
#pragma unroll
    for (int nt = 0; nt < 4; nt++) {
        svec8 kf0 = FRAG(Ks, nt * 16 + ln, quad);
        svec8 kf1 = FRAG(Ks, nt * 16 + ln, 4 + quad);
        const int sbase = nt * 16 + quad * 4;
#pragma unroll
        for (int qg = 0; qg < 4; qg++) {
            fvec4 z; z[0] = z[1] = z[2] = z[3] = 0.f;
            z = mfma16(kf0, qf[qg][0], z);
            z = mfma16(kf1, qf[qg][1], z);
            const int qcol = qg * 16 + ln;     // this lane's q column
            float p[4];
#pragma unroll
            for (int r = 0; r < 4; r++) {
                float y = z[r];
                float pv = fmaf(y, fmaf(y, 0.5f, 1.f), 1.f);   // e^y quadratic, |y|<=0.059
                if (DIAG && (sbase + r > qcol)) pv = 0.f;
                p[r] = pv;
            }
            uint2 u; u.x = pk2b(p[0], p[1]); u.y = pk2b(p[2], p[3]);
            const int paddr = (qcol << 6) | ((((sbase >> 3) ^ (qcol & 7))) << 3) | (sbase & 7);
            *(uint2*)(Psw + paddr) = u;
        }
    }
#pragma unroll
    for (int ks = 0; ks < 2; ks++) {
        svec8 pa[4];
#pragma unroll
        for (int qm = 0; qm < 4; qm++) {
            pa[qm] = FRAG(Psw, qm * 16 + ln, ks * 4 + quad);
            lacc[qm] = mfma16(pa[qm], ONES8, lacc[qm]);
        }
#pragma unroll
        for (int dkn = 0; dkn < 4; dkn++) {
            svec8 vf = FRAG(Vt, dkn * 16 + ln, ks * 4 + quad);
#pragma unroll
            for (int qm = 0; qm < 4; qm++)
                oacc[qm][dkn] = mfma16(pa[qm], vf, oacc[qm][dkn]);
        }
    }
}

__global__ __launch_bounds__(128)
void attn_kernel(const unsigned short* __restrict__ qkv, const unsigned short* __restrict__ vt,
                 unsigned short* __restrict__ o)
{
    // per-wave double-buffered K/V (8 KB each) + per-wave Ps; 80 KB total -> 2 blocks/CU
    __shared__ __align__(16) unsigned short Kb[2][2][4096];   // [wave][buf]
    __shared__ __align__(16) unsigned short Vb[2][2][4096];
    __shared__ __align__(16) unsigned short Ps[2][4096];
    // decode: c = fid&255 picks (bh, k); slot picks one of 4 qt so each c-group totals 66 steps.
    // bh & 7 == fid & 7 -> 4 heads per XCD (keeps R8's L2 locality win).
    const int fid = blockIdx.x;
    const int c = fid & 255, slot = fid >> 8, k = c >> 5;
    const int bh = c & 31;
    const int qt = (slot == 0) ? k : (slot == 1) ? 15 - k : (slot == 2) ? 16 + k : 31 - k;
    const int b = bh >> 3, hh = bh & 7;
    const int nst = qt + 1;
    const int tid = threadIdx.x, w = tid >> 6, lane = tid & 63, quad = lane >> 4, ln = lane & 15;
    const int jgz = (lane & 7) ^ (lane >> 3);

    // Q fragments straight from global into registers (64 q rows per wave)
    svec8 qf[4][2];
#pragma unroll
    for (int qg = 0; qg < 4; qg++) {
        const unsigned short* qp = qkv + ((size_t)(b * T + qt * 64 + qg * 16 + ln)) * QS2 + hh * 64;
        qf[qg][0] = *(const svec8*)(qp + quad * 8);
        qf[qg][1] = *(const svec8*)(qp + 32 + quad * 8);
    }

    // staging bases (lane-adjusted): K rows are s-rows; V rows are dk-rows, column = s*64
    const unsigned short* kbase = qkv + ((size_t)(b * T) + (lane >> 3)) * QS2 + 512 + hh * 64 + jgz * 8;
    const unsigned short* vbase = vt + ((size_t)(bh * 64) + (lane >> 3)) * T + jgz * 8;

    fvec4 oacc[4][4], lacc[4];
#pragma unroll
    for (int qm = 0; qm < 4; qm++) {
#pragma unroll
        for (int r = 0; r < 4; r++) lacc[qm][r] = 0.f;
#pragma unroll
        for (int dkn = 0; dkn < 4; dkn++)
#pragma unroll
            for (int r = 0; r < 4; r++) oacc[qm][dkn][r] = 0.f;
    }

    // wave w handles s = w, w+2, ... < nst; self-staged, no block barrier in the loop
    if (w < nst) {
        // prologue: stage first tile into buf 0
#pragma unroll
        for (int cc = 0; cc < 8; cc++) {
            glds16(kbase + ((size_t)(w * 64) + cc * 8) * QS2, Kb[w][0] + cc * 512);
            glds16(vbase + (size_t)(cc * 8) * T + w * 64, Vb[w][0] + cc * 512);
        }
        int buf = 0;
        for (int s = w; s < nst; s += 2, buf ^= 1) {
            const int snext = s + 2;
            const bool pre = (snext < nst);
            if (pre) {
#pragma unroll
                for (int cc = 0; cc < 8; cc++) {
                    glds16(kbase + ((size_t)(snext * 64) + cc * 8) * QS2, Kb[w][buf ^ 1] + cc * 512);
                    glds16(vbase + (size_t)(cc * 8) * T + snext * 64, Vb[w][buf ^ 1] + cc * 512);
                }
                WAITVM(16);    // drain current tile's 16; next's 16 stay in flight
            } else {
                WAITVM(0);
            }
            __builtin_amdgcn_sched_barrier(0);   // keep ds_reads below the waitcnt
            if (s == qt) attn_step64<true >(Ps[w], Kb[w][buf], Vb[w][buf], qf, oacc, lacc, quad, ln);
            else         attn_step64<false>(Ps[w], Kb[w][buf], Vb[w][buf], qf, oacc, lacc, quad, ln);
        }
    }

    // cross-wave reduction: even+odd s-partials are additive (no softmax max). Reuse Kb/Vb as fp32 scratch.
    __syncthreads();
    float* red = (float*)&Kb[0][0][0];     // 64 KB >= 2 x 20 KB
    float* mine = red + w * 5120 + lane * 80;
#pragma unroll
    for (int qm = 0; qm < 4; qm++) {
#pragma unroll
        for (int dkn = 0; dkn < 4; dkn++)
#pragma unroll
            for (int r = 0; r < 4; r++) mine[qm * 16 + dkn * 4 + r] = oacc[qm][dkn][r];
#pragma unroll
        for (int r = 0; r < 4; r++) mine[64 + qm * 4 + r] = lacc[qm][r];
    }
    __syncthreads();
    const float* other = red + (w ^ 1) * 5120 + lane * 80;
#pragma unroll
    for (int half = 0; half < 2; half++) {
        const int qm = w * 2 + half;
        float lsum[4];
#pragma unroll
        for (int r = 0; r < 4; r++) lsum[r] = lacc[qm][r] + other[64 + qm * 4 + r];
        unsigned short* og = o + (size_t)(b * T + qt * 64 + qm * 16 + quad * 4) * D + hh * 64;
#pragma unroll
        for (int r = 0; r < 4; r++) {
            float inv = 1.f / lsum[r];
#pragma unroll
            for (int dkn = 0; dkn < 4; dkn++) {
                float osum = oacc[qm][dkn][r] + other[qm * 16 + dkn * 4 + r];
                og[(size_t)r * D + dkn * 16 + ln] = f2b(osum * inv);
            }
        }
    }
}

// ---------------- masked-mean pool partials ----------------
__global__ __launch_bounds__(256)
void pool_kernel(const float* __restrict__ hn, const float* __restrict__ x, float* __restrict__ part)
{
    int b = blockIdx.x, ch = blockIdx.y, tid = threadIdx.x;
    int t0 = ch * 128;
    float s0 = 0.f, s1 = 0.f, cnt = 0.f;
    for (int tt = 0; tt < 128; tt++) {
        int t = t0 + tt;
        float xv = x[b * T + t];
        float m = (xv == -1.0f) ? 0.f : 1.f;
        cnt += m;
        const float* r = hn + ((size_t)(b * T + t)) * D;
        s0 += r[tid] * m;
        s1 += r[tid + 256] * m;
    }
    float* pr = part + (size_t)(b * 16 + ch) * 513;
    pr[tid] = s0; pr[tid + 256] = s1;
    if (tid == 0) pr[512] = cnt;
}

// ---------------- heads ----------------
__global__ __launch_bounds__(64)
void head_kernel(const float* __restrict__ part,
                 const float* __restrict__ bh_g, const float* __restrict__ bh_bl,
                 const float* __restrict__ ah_g, const float* __restrict__ ah_bl,
                 const float* __restrict__ ch_g, const float* __restrict__ ch_bl,
                 const float* __restrict__ bh_w, const float* __restrict__ bh_b2,
                 const float* __restrict__ ah_w, const float* __restrict__ ah_b2,
                 const float* __restrict__ ch_w, const float* __restrict__ ch_b2,
                 float* __restrict__ out)
{
    int b = blockIdx.x, lane = threadIdx.x;
    float cnt = 0.f;
    for (int c = 0; c < 16; c++) cnt += part[(size_t)(b * 16 + c) * 513 + 512];
    float denom = fmaxf(cnt, 1.f);
    float md[8];
    float s = 0.f, s2 = 0.f;
#pragma unroll
    for (int j = 0; j < 8; j++) {
        int d = j * 64 + lane;
        float acc = 0.f;
        for (int c = 0; c < 16; c++) acc += part[(size_t)(b * 16 + c) * 513 + d];
        md[j] = acc / denom;
        s += md[j]; s2 += md[j] * md[j];
    }
    s = wave_red_sum(s); s2 = wave_red_sum(s2);
    float mu = s * (1.f / 512.f);
    float var = s2 * (1.f / 512.f) - mu * mu;
    float rstd = 1.f / sqrtf(var + 1e-5f);
    float a0 = 0.f, a1 = 0.f, a2 = 0.f, a3 = 0.f;
#pragma unroll
    for (int j = 0; j < 8; j++) {
        int d = j * 64 + lane;
        float z = (md[j] - mu) * rstd;
        float zb = z * bh_g[d] + bh_bl[d];
        a0 += zb * bh_w[d * 2 + 0];
        a1 += zb * bh_w[d * 2 + 1];
        a2 += (z * ah_g[d] + ah_bl[d]) * ah_w[d];
        a3 += (z * ch_g[d] + ch_bl[d]) * ch_w[d];
    }
    a0 = wave_red_sum(a0); a1 = wave_red_sum(a1);
    a2 = wave_red_sum(a2); a3 = wave_red_sum(a3);
    if (lane == 0) {
        out[b * 4 + 0] = a0 + bh_b2[0];
        out[b * 4 + 1] = a1 + bh_b2[1];
        out[b * 4 + 2] = a2 + ah_b2[0];
        float t3 = a3 + ch_b2[0];
        out[b * 4 + 3] = 1.f / (1.f + expf(-t3));
    }
}

// ---------------- launch ----------------
extern "C" void kernel_launch(void* const* d_in, const int* in_sizes, int n_in,
                              void* d_out, int out_size, void* d_ws, size_t ws_size,
                              hipStream_t stream)
{
    const float* x      = (const float*)d_in[0];
    const float* ip_w   = (const float*)d_in[1];
    const float* ip_b   = (const float*)d_in[2];
    const float* ip_ln_g= (const float*)d_in[3];
    const float* ip_ln_b= (const float*)d_in[4];
    const float* pos    = (const float*)d_in[5];
    const float* pad_tok= (const float*)d_in[6];
    const float* Wq = (const float*)d_in[7];  const float* bq = (const float*)d_in[8];
    const float* Wk = (const float*)d_in[9];  const float* bk = (const float*)d_in[10];
    const float* Wv = (const float*)d_in[11]; const float* bv = (const float*)d_in[12];
    const float* Wo = (const float*)d_in[13]; const float* bo = (const float*)d_in[14];
    const float* ln1_g = (const float*)d_in[15]; const float* ln1_b = (const float*)d_in[16];
    const float* ln2_g = (const float*)d_in[17]; const float* ln2_b = (const float*)d_in[18];
    const float* W1 = (const float*)d_in[19]; const float* b1 = (const float*)d_in[20];
    const float* W2 = (const float*)d_in[21]; const float* b2 = (const float*)d_in[22];
    const float* gate1 = (const float*)d_in[23]; const float* gate2 = (const float*)d_in[24];
    const float* fn_g = (const float*)d_in[25]; const float* fn_b = (const float*)d_in[26];
    const float* bh_g  = (const float*)d_in[27]; const float* bh_bl = (const float*)d_in[28];
    const float* ah_g  = (const float*)d_in[29]; const float* ah_bl = (const float*)d_in[30];
    const float* ch_g  = (const float*)d_in[31]; const float* ch_bl = (const float*)d_in[32];
    const float* bh_w  = (const float*)d_in[33]; const float* bh_b2 = (const float*)d_in[34];
    const float* ah_w  = (const float*)d_in[35]; const float* ah_b2 = (const float*)d_in[36];
    const float* ch_w  = (const float*)d_in[37]; const float* ch_b2 = (const float*)d_in[38];

    char* ws = (char*)d_ws;
    float*          h     = (float*)ws;                       // 16 MB fp32 [8192][512]
    unsigned short* act_b = (unsigned short*)(ws + 16777216); // 8 MB bf16 [8192][512]
    unsigned short* qkv   = (unsigned short*)(ws + 25165824); // 16 MB bf16 [8192][1024] (q|k)
    unsigned short* mid_b = (unsigned short*)(ws + 41943040); // 32 MB bf16 [8192][2048]
    float*          xn_f  = (float*)(ws + 41943040);          // 16 MB alias (final LN only)
    unsigned short* wT    = (unsigned short*)(ws + 75497472); // 6 MB per-layer transposed weights
    unsigned short* vt    = (unsigned short*)(ws + 81788928); // 8 MB bf16 [4*512][2048]
    float*          part  = (float*)(ws + 90177536);
    float*          out   = (float*)d_out;

    unsigned short* wqT = wT;             // [1536][512] (q,k,v contiguous)
    unsigned short* wkT = wT + 262144;
    unsigned short* wvT = wT + 524288;
    unsigned short* woT = wT + 786432;
    unsigned short* w1T = wT + 1048576;   // [2048][512]
    unsigned short* w2T = wT + 2097152;   // [512][2048]

    embed_kernel<<<dim3(Bsz * T), dim3(64), 0, stream>>>(x, ip_w, ip_b, ip_ln_g, ip_ln_b, pos, pad_tok, h);

    for (int i = 0; i < Lnum; i++) {
        const size_t dd = (size_t)i * D * D;
        const size_t df = (size_t)i * D * DFF;
        prep_kernel<<<dim3(5120), dim3(256), 0, stream>>>(Wq + dd, Wk + dd, Wv + dd, Wo + dd,
                                                          W1 + df, W2 + df,
                                                          wqT, wkT, wvT, woT, w1T, w2T,
                                                          h, act_b, ln1_g + i * D, ln1_b + i * D);
        gemm_bf16<0, 1, 128><<<dim3(64, 12), dim3(256), 0, stream>>>(act_b, wqT, bq + i * D, bk + i * D, bv + i * D,
                                                                     nullptr, qkv, vt, Bsz * T, 1536, D, nullptr);
        attn_kernel<<<dim3(1024), dim3(128), 0, stream>>>(qkv, vt, act_b);
        gemm_bf16<1, 0, 64><<<dim3(128, 4), dim3(256), 0, stream>>>(act_b, woT, bo + i * D, nullptr, nullptr,
                                                                    h, h, nullptr, Bsz * T, D, D, gate1 + i);
        ln_bf16_kernel<<<dim3(Bsz * T / 4), dim3(256), 0, stream>>>(h, act_b, ln2_g + i * D, ln2_b + i * D);
        gemm_bf16<2, 1, 128><<<dim3(64, 16), dim3(256), 0, stream>>>(act_b, w1T, b1 + i * DFF, nullptr, nullptr,
                                                                     nullptr, mid_b, nullptr, Bsz * T, DFF, D, nullptr);
        gemm_bf16<3, 0, 64><<<dim3(128, 4), dim3(256), 0, stream>>>(mid_b, w2T, b2 + i * D, nullptr, nullptr,
                                                                    h, h, nullptr, Bsz * T, D, DFF, gate2 + i);
    }

    ln_kernel<<<dim3(Bsz * T / 4), dim3(256), 0, stream>>>(h, xn_f, fn_g, fn_b);
    pool_kernel<<<dim3(Bsz, 16), dim3(256), 0, stream>>>(xn_f, x, part);
    head_kernel<<<dim3(Bsz), dim3(64), 0, stream>>>(part, bh_g, bh_bl, ah_g, ah_bl, ch_g, ch_bl,
                                                    bh_w, bh_b2, ah_w, ah_b2, ch_w, ch_b2, out);
}

// Round 11
// 1182.176 us; speedup vs baseline: 1.1127x; 1.1127x over previous
//
#include <hip/hip_runtime.h>
#include <hip/hip_bf16.h>
#include <math.h>

// ---------------- constants ----------------
constexpr int Bsz = 4, T = 2048, D = 512, H = 8, Lnum = 6, DFF = 2048, DK = 64;
constexpr int QS2 = 1024;                       // qkv row stride (q at 0, k at 512; v goes to vt)
constexpr float K2 = 0.08838834764831845f / 1.5f;  // softmax exponent scale (folded into q)

typedef __attribute__((ext_vector_type(8))) short svec8;   // 8 bf16 (4 VGPRs)
typedef __attribute__((ext_vector_type(4))) float fvec4;   // 4 fp32 acc

__device__ __forceinline__ fvec4 mfma16(svec8 a, svec8 b, fvec4 c) {
    return __builtin_amdgcn_mfma_f32_16x16x32_bf16(a, b, c, 0, 0, 0);
}
__device__ __forceinline__ unsigned short f2b(float f) {
    unsigned int u = __float_as_uint(f);
    u += 0x7fffu + ((u >> 16) & 1u);
    return (unsigned short)(u >> 16);
}
__device__ __forceinline__ unsigned int pk2b(float a, float b) {
    __hip_bfloat162 h = __float22bfloat162_rn(float2{a, b});
    return *(unsigned int*)&h;
}
__device__ __forceinline__ float wave_red_sum(float v) {
    for (int o = 32; o > 0; o >>= 1) v += __shfl_down(v, o, 64);
    return __shfl(v, 0, 64);
}
// async global->LDS, 16B per lane; lds base must be wave-uniform (HW adds lane*16)
__device__ __forceinline__ void glds16(const unsigned short* g, unsigned short* l) {
    __builtin_amdgcn_global_load_lds(
        (const __attribute__((address_space(1))) unsigned int*)g,
        (__attribute__((address_space(3))) unsigned int*)l, 16, 0, 0);
}
// swizzled-tile fragment read: 64-wide rows, chunk kq of row r at slot kq^(r&7)
#define FRAG(buf, row, kq) (*(const svec8*)((buf) + (((row) << 6) | ((((kq) ^ ((row) & 7))) << 3))))

// ---------------- embed (fp32 h) ----------------
__global__ __launch_bounds__(64)
void embed_kernel(const float* __restrict__ x, const float* __restrict__ ip_w,
                  const float* __restrict__ ip_b, const float* __restrict__ g,
                  const float* __restrict__ bta, const float* __restrict__ pos,
                  const float* __restrict__ pad_tok, float* __restrict__ h)
{
    int row = blockIdx.x;
    int t = row & (T - 1);
    int lane = threadIdx.x;
    float xv = x[row];
    float xc = fminf(fmaxf(xv, -10.f), 10.f);
    bool pad = (xc == -1.0f);
    float pre[8];
    float s = 0.f, s2 = 0.f;
#pragma unroll
    for (int j = 0; j < 8; j++) {
        int d = j * 64 + lane;
        float p = xc * ip_w[d] + ip_b[d];
        pre[j] = p; s += p; s2 += p * p;
    }
    s = wave_red_sum(s); s2 = wave_red_sum(s2);
    float m = s * (1.f / 512.f);
    float var = s2 * (1.f / 512.f) - m * m;
    float rstd = 1.f / sqrtf(var + 1e-5f);
#pragma unroll
    for (int j = 0; j < 8; j++) {
        int d = j * 64 + lane;
        float hv = (pre[j] - m) * rstd * g[d] + bta[d] + 0.1f * pos[(size_t)t * D + d];
        if (pad) hv = pad_tok[d];
        h[(size_t)row * D + d] = hv;
    }
}

// ---------------- LayerNorm fp32 -> fp32 (final), 4 rows/block ----------------
__global__ __launch_bounds__(256)
void ln_kernel(const float* __restrict__ in, float* __restrict__ out,
               const float* __restrict__ g, const float* __restrict__ b)
{
    int row = blockIdx.x * 4 + (threadIdx.x >> 6);
    int lane = threadIdx.x & 63;
    const float* r = in + (size_t)row * D;
    float4 v0 = ((const float4*)r)[lane];
    float4 v1 = ((const float4*)r)[lane + 64];
    float s = v0.x + v0.y + v0.z + v0.w + v1.x + v1.y + v1.z + v1.w;
    float s2 = v0.x*v0.x + v0.y*v0.y + v0.z*v0.z + v0.w*v0.w
             + v1.x*v1.x + v1.y*v1.y + v1.z*v1.z + v1.w*v1.w;
    s = wave_red_sum(s); s2 = wave_red_sum(s2);
    float m = s * (1.f / 512.f);
    float var = s2 * (1.f / 512.f) - m * m;
    float rstd = 1.f / sqrtf(var + 1e-5f);
    float4 g0 = ((const float4*)g)[lane], g1 = ((const float4*)g)[lane + 64];
    float4 b0 = ((const float4*)b)[lane], b1 = ((const float4*)b)[lane + 64];
    float4 o0, o1;
    o0.x = (v0.x - m) * rstd * g0.x + b0.x; o0.y = (v0.y - m) * rstd * g0.y + b0.y;
    o0.z = (v0.z - m) * rstd * g0.z + b0.z; o0.w = (v0.w - m) * rstd * g0.w + b0.w;
    o1.x = (v1.x - m) * rstd * g1.x + b1.x; o1.y = (v1.y - m) * rstd * g1.y + b1.y;
    o1.z = (v1.z - m) * rstd * g1.z + b1.z; o1.w = (v1.w - m) * rstd * g1.w + b1.w;
    ((float4*)(out + (size_t)row * D))[lane] = o0;
    ((float4*)(out + (size_t)row * D))[lane + 64] = o1;
}

// ---------------- device LN fp32 -> bf16 helper (one wave, one row) ----------------
__device__ __forceinline__ void ln_row_bf16(const float* __restrict__ in, unsigned short* __restrict__ out,
                                            const float* __restrict__ g, const float* __restrict__ b,
                                            int row, int lane)
{
    const float* r = in + (size_t)row * D;
    float4 v0 = ((const float4*)r)[lane];
    float4 v1 = ((const float4*)r)[lane + 64];
    float s = v0.x + v0.y + v0.z + v0.w + v1.x + v1.y + v1.z + v1.w;
    float s2 = v0.x*v0.x + v0.y*v0.y + v0.z*v0.z + v0.w*v0.w
             + v1.x*v1.x + v1.y*v1.y + v1.z*v1.z + v1.w*v1.w;
    s = wave_red_sum(s); s2 = wave_red_sum(s2);
    float m = s * (1.f / 512.f);
    float var = s2 * (1.f / 512.f) - m * m;
    float rstd = 1.f / sqrtf(var + 1e-5f);
    float4 g0 = ((const float4*)g)[lane], g1 = ((const float4*)g)[lane + 64];
    float4 b0 = ((const float4*)b)[lane], b1 = ((const float4*)b)[lane + 64];
    unsigned short o0[4], o1[4];
    o0[0] = f2b((v0.x - m) * rstd * g0.x + b0.x); o0[1] = f2b((v0.y - m) * rstd * g0.y + b0.y);
    o0[2] = f2b((v0.z - m) * rstd * g0.z + b0.z); o0[3] = f2b((v0.w - m) * rstd * g0.w + b0.w);
    o1[0] = f2b((v1.x - m) * rstd * g1.x + b1.x); o1[1] = f2b((v1.y - m) * rstd * g1.y + b1.y);
    o1[2] = f2b((v1.z - m) * rstd * g1.z + b1.z); o1[3] = f2b((v1.w - m) * rstd * g1.w + b1.w);
    *(uint2*)(out + (size_t)row * D + lane * 4) = *(uint2*)o0;
    *(uint2*)(out + (size_t)row * D + 256 + lane * 4) = *(uint2*)o1;
}

__global__ __launch_bounds__(256)
void ln_bf16_kernel(const float* __restrict__ in, unsigned short* __restrict__ out,
                    const float* __restrict__ g, const float* __restrict__ b)
{
    ln_row_bf16(in, out, g, b, blockIdx.x * 4 + (threadIdx.x >> 6), threadIdx.x & 63);
}

// ---------------- fused per-layer prep: wconv (bid<3072) + ln1 (bid in [3072,5120)) ----------------
__global__ __launch_bounds__(256)
void prep_kernel(const float* __restrict__ wq, const float* __restrict__ wk,
                 const float* __restrict__ wv, const float* __restrict__ wo,
                 const float* __restrict__ w1, const float* __restrict__ w2,
                 unsigned short* __restrict__ oq, unsigned short* __restrict__ ok,
                 unsigned short* __restrict__ ov, unsigned short* __restrict__ oo,
                 unsigned short* __restrict__ o1, unsigned short* __restrict__ o2,
                 const float* __restrict__ hin, unsigned short* __restrict__ lnout,
                 const float* __restrict__ ln_g, const float* __restrict__ ln_b)
{
    __shared__ float tile[32][33];
    int bid = blockIdx.x;
    if (bid >= 3072) {
        int row = (bid - 3072) * 4 + (threadIdx.x >> 6);
        ln_row_bf16(hin, lnout, ln_g, ln_b, row, threadIdx.x & 63);
        return;
    }
    const float* in; unsigned short* out; int K, N, kt, nt;
    if (bid < 1024) {
        int sel = bid >> 8, loc = bid & 255;
        in  = sel == 0 ? wq : sel == 1 ? wk : sel == 2 ? wv : wo;
        out = sel == 0 ? oq : sel == 1 ? ok : sel == 2 ? ov : oo;
        K = 512; N = 512; kt = loc >> 4; nt = loc & 15;
    } else if (bid < 2048) {
        int loc = bid - 1024; in = w1; out = o1; K = 512; N = 2048; kt = loc >> 6; nt = loc & 63;
    } else {
        int loc = bid - 2048; in = w2; out = o2; K = 2048; N = 512; kt = loc >> 4; nt = loc & 15;
    }
    int k0 = kt * 32, n0 = nt * 32;
    int t = threadIdx.x;
    int kr = t >> 3, nc = (t & 7) * 4;
    float4 v = *(const float4*)(in + (size_t)(k0 + kr) * N + n0 + nc);
    tile[kr][nc] = v.x; tile[kr][nc + 1] = v.y; tile[kr][nc + 2] = v.z; tile[kr][nc + 3] = v.w;
    __syncthreads();
    unsigned short o[4];
#pragma unroll
    for (int i = 0; i < 4; i++) o[i] = f2b(tile[nc + i][kr]);
    *(uint2*)(out + (size_t)(n0 + kr) * K + k0 + nc) = *(uint2*)o;
}

// ---------------- bf16 MFMA GEMM, global_load_lds + BK=64 XOR swizzle ----------------
template<int EPI, int OBF, int BM>
__global__ __launch_bounds__(256)
void gemm_bf16(const unsigned short* __restrict__ A, const unsigned short* __restrict__ BT,
               const float* __restrict__ bias, const float* __restrict__ bias_b,
               const float* __restrict__ bias_c, const float* __restrict__ res,
               void* __restrict__ Cv, unsigned short* __restrict__ vtout,
               int M, int N, int K, const float* __restrict__ gate_p)
{
    constexpr int WN = (BM == 128) ? 2 : 4;
    constexpr int WSPAN = 128 / WN;
    constexpr int NT = WSPAN / 16;
    constexpr int MT = 4;
    constexpr int ACALLS = BM / 32;
    constexpr int SMEMSZ = (EPI == 0) ? 17408 : (BM * 64 + 128 * 64);
    __shared__ __align__(16) unsigned short SMEM[SMEMSZ];
    unsigned short* As = SMEM;
    unsigned short* Bs = SMEM + BM * 64;
    const int tid = threadIdx.x, w = tid >> 6, lane = tid & 63, quad = lane >> 4, ln = lane & 15;
    const int wm = w / WN, wn = w % WN;
    const int m0 = blockIdx.x * BM, n0 = blockIdx.y * 128;
    const int jg = (lane & 7) ^ ((lane >> 3) & 7);
    const int rb = w * 8 + (lane >> 3);
    const unsigned short* Agl = A + (size_t)(m0 + rb) * K + jg * 8;
    const unsigned short* Bgl = BT + (size_t)(n0 + rb) * K + jg * 8;

    fvec4 acc[MT][NT];
#pragma unroll
    for (int mt = 0; mt < MT; mt++)
#pragma unroll
        for (int nt = 0; nt < NT; nt++)
#pragma unroll
            for (int r = 0; r < 4; r++) acc[mt][nt][r] = 0.f;

    for (int k0 = 0; k0 < K; k0 += 64) {
        __syncthreads();
#pragma unroll
        for (int c = 0; c < ACALLS; c++)
            glds16(Agl + k0 + (size_t)c * 32 * K, As + c * 2048 + w * 512);
#pragma unroll
        for (int c = 0; c < 4; c++)
            glds16(Bgl + k0 + (size_t)c * 32 * K, Bs + c * 2048 + w * 512);
        __syncthreads();
#pragma unroll
        for (int kk = 0; kk < 2; kk++) {
            svec8 af[MT], bfr[NT];
#pragma unroll
            for (int mt = 0; mt < MT; mt++)
                af[mt] = FRAG(As, wm * 64 + mt * 16 + ln, kk * 4 + quad);
#pragma unroll
            for (int nt = 0; nt < NT; nt++)
                bfr[nt] = FRAG(Bs, wn * WSPAN + nt * 16 + ln, kk * 4 + quad);
#pragma unroll
            for (int mt = 0; mt < MT; mt++)
#pragma unroll
                for (int nt = 0; nt < NT; nt++)
                    acc[mt][nt] = mfma16(af[mt], bfr[nt], acc[mt][nt]);
        }
    }

    const float gate = (EPI == 1 || EPI == 3) ? gate_p[0] : 0.f;
    float bb[NT];
#pragma unroll
    for (int nt = 0; nt < NT; nt++) {
        int n = n0 + wn * WSPAN + nt * 16 + ln;
        if (EPI == 0) {
            int nseg = n >> 9;
            const float* bsel = nseg == 0 ? bias : (nseg == 1 ? bias_b : bias_c);
            bb[nt] = bsel[n - nseg * 512];
        } else {
            bb[nt] = bias[n];
        }
    }

    if (EPI == 0 && n0 >= 1024) {
        __syncthreads();
#pragma unroll
        for (int mt = 0; mt < MT; mt++) {
#pragma unroll
            for (int nt = 0; nt < NT; nt++) {
                int nl = wn * 64 + nt * 16 + ln;
                int mb = wm * 64 + mt * 16 + quad * 4;
                unsigned int lo = pk2b(acc[mt][nt][0] + bb[nt], acc[mt][nt][1] + bb[nt]);
                unsigned int hi = pk2b(acc[mt][nt][2] + bb[nt], acc[mt][nt][3] + bb[nt]);
                uint2 u; u.x = lo; u.y = hi;
                *(uint2*)(SMEM + nl * 136 + mb) = u;
            }
        }
        __syncthreads();
        int row = tid >> 1, half = (tid & 1) * 64;
        unsigned short* dst = vtout + ((size_t)((m0 >> 11) * 512 + (n0 - 1024) + row)) * T
                              + (m0 & (T - 1)) + half;
        const unsigned short* src = SMEM + row * 136 + half;
#pragma unroll
        for (int j = 0; j < 8; j++) *(uint4*)(dst + j * 8) = *(const uint4*)(src + j * 8);
        return;
    }

#pragma unroll
    for (int mt = 0; mt < MT; mt++) {
        float v[NT][4];
#pragma unroll
        for (int nt = 0; nt < NT; nt++)
#pragma unroll
            for (int r = 0; r < 4; r++) v[nt][r] = acc[mt][nt][r] + bb[nt];
        if (EPI == 0) {   // q/k: fused L2 norm; q additionally pre-scaled by K2
            const float fac = ((n0 + wn * WSPAN) < 512) ? K2 : 1.f;
#pragma unroll
            for (int r = 0; r < 4; r++) {
                float s = 0.f;
#pragma unroll
                for (int nt = 0; nt < NT; nt++) s += v[nt][r] * v[nt][r];
                s += __shfl_xor(s, 1); s += __shfl_xor(s, 2);
                s += __shfl_xor(s, 4); s += __shfl_xor(s, 8);
                float rs = fac / fmaxf(sqrtf(s), 1e-8f);
#pragma unroll
                for (int nt = 0; nt < NT; nt++) v[nt][r] *= rs;
            }
        }
#pragma unroll
        for (int nt = 0; nt < NT; nt++) {
            int n = n0 + wn * WSPAN + nt * 16 + ln;
#pragma unroll
            for (int r = 0; r < 4; r++) {
                int m = m0 + wm * 64 + mt * 16 + quad * 4 + r;
                float val = v[nt][r];
                if (EPI == 0) {
                    ((unsigned short*)Cv)[(size_t)m * QS2 + n] = f2b(val);
                } else {
                    size_t off = (size_t)m * N + n;
                    if (EPI == 1) val = res[off] + gate * 0.5f * val;
                    else if (EPI == 2) {
                        float u = val;
                        float z = 0.7978845608028654f * fmaf(0.044715f * u, u * u, u);
                        float e = __builtin_amdgcn_exp2f(z * 2.8853900817779268f);
                        float rr = __builtin_amdgcn_rcpf(e + 1.f);
                        val = u * (1.f - rr);
                    }
                    else if (EPI == 3) val = fminf(fmaxf(res[off] + gate * val, -10.f), 10.f);
                    if (OBF) ((unsigned short*)Cv)[off] = f2b(val);
                    else ((float*)Cv)[off] = val;
                }
            }
        }
    }
}

// ---------------- flash attention v2': one qt/block, 2 waves x 32 static q-rows ----------------
// All accumulator indexing compile-time (no scratch spill); wave id enters addresses only.
template<bool DIAG>
__device__ __forceinline__ void attn_step32(
    unsigned short* Ps, const unsigned short* Ks, const unsigned short* Vt,
    const svec8 (&qf)[2][2], fvec4 (&oacc)[2][4], fvec4 (&lacc)[2],
    int w, int quad, int ln)
{
    constexpr short BONE = (short)0x3F80;     // bf16 1.0
    const svec8 ONES8 = {BONE, BONE, BONE, BONE, BONE, BONE, BONE, BONE};
#pragma unroll
    for (int nt = 0; nt < 4; nt++) {
        svec8 kf0 = FRAG(Ks, nt * 16 + ln, quad);
        svec8 kf1 = FRAG(Ks, nt * 16 + ln, 4 + quad);
        const int sbase = nt * 16 + quad * 4;
#pragma unroll
        for (int qg = 0; qg < 2; qg++) {
            fvec4 z; z[0] = z[1] = z[2] = z[3] = 0.f;
            z = mfma16(kf0, qf[qg][0], z);
            z = mfma16(kf1, qf[qg][1], z);
            const int qcol = w * 32 + qg * 16 + ln;   // this lane's q row (as P row)
            float p[4];
#pragma unroll
            for (int r = 0; r < 4; r++) {
                float y = z[r];
                float pv = fmaf(y, fmaf(y, 0.5f, 1.f), 1.f);   // e^y quadratic, |y|<=0.059
                if (DIAG && (sbase + r > qcol)) pv = 0.f;
                p[r] = pv;
            }
            uint2 u; u.x = pk2b(p[0], p[1]); u.y = pk2b(p[2], p[3]);
            const int paddr = (qcol << 6) | ((((sbase >> 3) ^ (qcol & 7))) << 3) | (sbase & 7);
            *(uint2*)(Ps + paddr) = u;
        }
    }
#pragma unroll
    for (int ks = 0; ks < 2; ks++) {
        svec8 pa[2];
#pragma unroll
        for (int qg = 0; qg < 2; qg++) {
            pa[qg] = FRAG(Ps, w * 32 + qg * 16 + ln, ks * 4 + quad);
            lacc[qg] = mfma16(pa[qg], ONES8, lacc[qg]);
        }
#pragma unroll
        for (int dkn = 0; dkn < 4; dkn++) {
            svec8 vf = FRAG(Vt, dkn * 16 + ln, ks * 4 + quad);
#pragma unroll
            for (int qg = 0; qg < 2; qg++)
                oacc[qg][dkn] = mfma16(pa[qg], vf, oacc[qg][dkn]);
        }
    }
}

__global__ __launch_bounds__(128)
void attn_kernel(const unsigned short* __restrict__ qkv, const unsigned short* __restrict__ vt,
                 unsigned short* __restrict__ o)
{
    // 40 KB LDS -> 4 blocks/CU x 2 waves = 8 waves/CU
    __shared__ __align__(16) unsigned short K0[4096], V0[4096], K1[4096], V1[4096];
    __shared__ __align__(16) unsigned short Ps[4096];   // wave w owns rows w*32..w*32+31
    // decode: 4 heads per XCD; per c-group the 4 qt slots total 66 steps (balanced)
    const int fid = blockIdx.x;
    const int c = fid & 255, slot = fid >> 8, k = c >> 5;
    const int bh = c & 31;
    const int qt = (slot == 0) ? k : (slot == 1) ? 15 - k : (slot == 2) ? 16 + k : 31 - k;
    const int b = bh >> 3, hh = bh & 7;
    const int nst = qt + 1;
    const int tid = threadIdx.x, w = tid >> 6, lane = tid & 63, quad = lane >> 4, ln = lane & 15;
    const int jgz = (lane & 7) ^ (lane >> 3);

    // Q fragments for this wave's 32 q-rows, straight from global
    svec8 qf[2][2];
#pragma unroll
    for (int qg = 0; qg < 2; qg++) {
        const unsigned short* qp = qkv + ((size_t)(b * T + qt * 64 + w * 32 + qg * 16 + ln)) * QS2 + hh * 64;
        qf[qg][0] = *(const svec8*)(qp + quad * 8);
        qf[qg][1] = *(const svec8*)(qp + 32 + quad * 8);
    }

    // staging bases: each wave stages rows {w*8+(lane>>3)} + 16*cc of each tile
    const unsigned short* kbase = qkv + ((size_t)(b * T) + w * 8 + (lane >> 3)) * QS2 + 512 + hh * 64 + jgz * 8;
    const unsigned short* vbase = vt + ((size_t)(bh * 64) + w * 8 + (lane >> 3)) * T + jgz * 8;
    const int ldsoff = w * 8 * 64;   // wave's 8-row slice within each 16-row call group

    fvec4 oacc[2][4], lacc[2];
#pragma unroll
    for (int qg = 0; qg < 2; qg++) {
#pragma unroll
        for (int r = 0; r < 4; r++) lacc[qg][r] = 0.f;
#pragma unroll
        for (int dkn = 0; dkn < 4; dkn++)
#pragma unroll
            for (int r = 0; r < 4; r++) oacc[qg][dkn][r] = 0.f;
    }

    const int Nph = (nst + 1) >> 1;
    for (int ph = 0; ph < Nph; ph++) {
        const int s0 = 2 * ph, s1 = 2 * ph + 1;
        __syncthreads();   // previous phase's reads of K/V done
#pragma unroll
        for (int cc = 0; cc < 4; cc++) {
            glds16(kbase + ((size_t)(s0 * 64) + cc * 16) * QS2, K0 + cc * 1024 + ldsoff);
            glds16(vbase + (size_t)(cc * 16) * T + s0 * 64, V0 + cc * 1024 + ldsoff);
        }
        if (s1 < nst) {
#pragma unroll
            for (int cc = 0; cc < 4; cc++) {
                glds16(kbase + ((size_t)(s1 * 64) + cc * 16) * QS2, K1 + cc * 1024 + ldsoff);
                glds16(vbase + (size_t)(cc * 16) * T + s1 * 64, V1 + cc * 1024 + ldsoff);
            }
        }
        __syncthreads();   // staged data visible
        if (s0 == qt) attn_step32<true >(Ps, K0, V0, qf, oacc, lacc, w, quad, ln);
        else          attn_step32<false>(Ps, K0, V0, qf, oacc, lacc, w, quad, ln);
        if (s1 < nst) {
            if (s1 == qt) attn_step32<true >(Ps, K1, V1, qf, oacc, lacc, w, quad, ln);
            else          attn_step32<false>(Ps, K1, V1, qf, oacc, lacc, w, quad, ln);
        }
    }

    // direct epilogue — each wave fully owns its 32 q rows (no cross-wave reduction)
    unsigned short* og = o + (size_t)(b * T + qt * 64 + w * 32 + quad * 4) * D + hh * 64;
#pragma unroll
    for (int qg = 0; qg < 2; qg++) {
#pragma unroll
        for (int r = 0; r < 4; r++) {
            float inv = 1.f / lacc[qg][r];
#pragma unroll
            for (int dkn = 0; dkn < 4; dkn++)
                og[(size_t)(qg * 16 + r) * D + dkn * 16 + ln] = f2b(oacc[qg][dkn][r] * inv);
        }
    }
}

// ---------------- masked-mean pool partials ----------------
__global__ __launch_bounds__(256)
void pool_kernel(const float* __restrict__ hn, const float* __restrict__ x, float* __restrict__ part)
{
    int b = blockIdx.x, ch = blockIdx.y, tid = threadIdx.x;
    int t0 = ch * 128;
    float s0 = 0.f, s1 = 0.f, cnt = 0.f;
    for (int tt = 0; tt < 128; tt++) {
        int t = t0 + tt;
        float xv = x[b * T + t];
        float m = (xv == -1.0f) ? 0.f : 1.f;
        cnt += m;
        const float* r = hn + ((size_t)(b * T + t)) * D;
        s0 += r[tid] * m;
        s1 += r[tid + 256] * m;
    }
    float* pr = part + (size_t)(b * 16 + ch) * 513;
    pr[tid] = s0; pr[tid + 256] = s1;
    if (tid == 0) pr[512] = cnt;
}

// ---------------- heads ----------------
__global__ __launch_bounds__(64)
void head_kernel(const float* __restrict__ part,
                 const float* __restrict__ bh_g, const float* __restrict__ bh_bl,
                 const float* __restrict__ ah_g, const float* __restrict__ ah_bl,
                 const float* __restrict__ ch_g, const float* __restrict__ ch_bl,
                 const float* __restrict__ bh_w, const float* __restrict__ bh_b2,
                 const float* __restrict__ ah_w, const float* __restrict__ ah_b2,
                 const float* __restrict__ ch_w, const float* __restrict__ ch_b2,
                 float* __restrict__ out)
{
    int b = blockIdx.x, lane = threadIdx.x;
    float cnt = 0.f;
    for (int c = 0; c < 16; c++) cnt += part[(size_t)(b * 16 + c) * 513 + 512];
    float denom = fmaxf(cnt, 1.f);
    float md[8];
    float s = 0.f, s2 = 0.f;
#pragma unroll
    for (int j = 0; j < 8; j++) {
        int d = j * 64 + lane;
        float acc = 0.f;
        for (int c = 0; c < 16; c++) acc += part[(size_t)(b * 16 + c) * 513 + d];
        md[j] = acc / denom;
        s += md[j]; s2 += md[j] * md[j];
    }
    s = wave_red_sum(s); s2 = wave_red_sum(s2);
    float mu = s * (1.f / 512.f);
    float var = s2 * (1.f / 512.f) - mu * mu;
    float rstd = 1.f / sqrtf(var + 1e-5f);
    float a0 = 0.f, a1 = 0.f, a2 = 0.f, a3 = 0.f;
#pragma unroll
    for (int j = 0; j < 8; j++) {
        int d = j * 64 + lane;
        float z = (md[j] - mu) * rstd;
        float zb = z * bh_g[d] + bh_bl[d];
        a0 += zb * bh_w[d * 2 + 0];
        a1 += zb * bh_w[d * 2 + 1];
        a2 += (z * ah_g[d] + ah_bl[d]) * ah_w[d];
        a3 += (z * ch_g[d] + ch_bl[d]) * ch_w[d];
    }
    a0 = wave_red_sum(a0); a1 = wave_red_sum(a1);
    a2 = wave_red_sum(a2); a3 = wave_red_sum(a3);
    if (lane == 0) {
        out[b * 4 + 0] = a0 + bh_b2[0];
        out[b * 4 + 1] = a1 + bh_b2[1];
        out[b * 4 + 2] = a2 + ah_b2[0];
        float t3 = a3 + ch_b2[0];
        out[b * 4 + 3] = 1.f / (1.f + expf(-t3));
    }
}

// ---------------- launch ----------------
extern "C" void kernel_launch(void* const* d_in, const int* in_sizes, int n_in,
                              void* d_out, int out_size, void* d_ws, size_t ws_size,
                              hipStream_t stream)
{
    const float* x      = (const float*)d_in[0];
    const float* ip_w   = (const float*)d_in[1];
    const float* ip_b   = (const float*)d_in[2];
    const float* ip_ln_g= (const float*)d_in[3];
    const float* ip_ln_b= (const float*)d_in[4];
    const float* pos    = (const float*)d_in[5];
    const float* pad_tok= (const float*)d_in[6];
    const float* Wq = (const float*)d_in[7];  const float* bq = (const float*)d_in[8];
    const float* Wk = (const float*)d_in[9];  const float* bk = (const float*)d_in[10];
    const float* Wv = (const float*)d_in[11]; const float* bv = (const float*)d_in[12];
    const float* Wo = (const float*)d_in[13]; const float* bo = (const float*)d_in[14];
    const float* ln1_g = (const float*)d_in[15]; const float* ln1_b = (const float*)d_in[16];
    const float* ln2_g = (const float*)d_in[17]; const float* ln2_b = (const float*)d_in[18];
    const float* W1 = (const float*)d_in[19]; const float* b1 = (const float*)d_in[20];
    const float* W2 = (const float*)d_in[21]; const float* b2 = (const float*)d_in[22];
    const float* gate1 = (const float*)d_in[23]; const float* gate2 = (const float*)d_in[24];
    const float* fn_g = (const float*)d_in[25]; const float* fn_b = (const float*)d_in[26];
    const float* bh_g  = (const float*)d_in[27]; const float* bh_bl = (const float*)d_in[28];
    const float* ah_g  = (const float*)d_in[29]; const float* ah_bl = (const float*)d_in[30];
    const float* ch_g  = (const float*)d_in[31]; const float* ch_bl = (const float*)d_in[32];
    const float* bh_w  = (const float*)d_in[33]; const float* bh_b2 = (const float*)d_in[34];
    const float* ah_w  = (const float*)d_in[35]; const float* ah_b2 = (const float*)d_in[36];
    const float* ch_w  = (const float*)d_in[37]; const float* ch_b2 = (const float*)d_in[38];

    char* ws = (char*)d_ws;
    float*          h     = (float*)ws;                       // 16 MB fp32 [8192][512]
    unsigned short* act_b = (unsigned short*)(ws + 16777216); // 8 MB bf16 [8192][512]
    unsigned short* qkv   = (unsigned short*)(ws + 25165824); // 16 MB bf16 [8192][1024] (q|k)
    unsigned short* mid_b = (unsigned short*)(ws + 41943040); // 32 MB bf16 [8192][2048]
    float*          xn_f  = (float*)(ws + 41943040);          // 16 MB alias (final LN only)
    unsigned short* wT    = (unsigned short*)(ws + 75497472); // 6 MB per-layer transposed weights
    unsigned short* vt    = (unsigned short*)(ws + 81788928); // 8 MB bf16 [4*512][2048]
    float*          part  = (float*)(ws + 90177536);
    float*          out   = (float*)d_out;

    unsigned short* wqT = wT;             // [1536][512] (q,k,v contiguous)
    unsigned short* wkT = wT + 262144;
    unsigned short* wvT = wT + 524288;
    unsigned short* woT = wT + 786432;
    unsigned short* w1T = wT + 1048576;   // [2048][512]
    unsigned short* w2T = wT + 2097152;   // [512][2048]

    embed_kernel<<<dim3(Bsz * T), dim3(64), 0, stream>>>(x, ip_w, ip_b, ip_ln_g, ip_ln_b, pos, pad_tok, h);

    for (int i = 0; i < Lnum; i++) {
        const size_t dd = (size_t)i * D * D;
        const size_t df = (size_t)i * D * DFF;
        prep_kernel<<<dim3(5120), dim3(256), 0, stream>>>(Wq + dd, Wk + dd, Wv + dd, Wo + dd,
                                                          W1 + df, W2 + df,
                                                          wqT, wkT, wvT, woT, w1T, w2T,
                                                          h, act_b, ln1_g + i * D, ln1_b + i * D);
        gemm_bf16<0, 1, 128><<<dim3(64, 12), dim3(256), 0, stream>>>(act_b, wqT, bq + i * D, bk + i * D, bv + i * D,
                                                                     nullptr, qkv, vt, Bsz * T, 1536, D, nullptr);
        attn_kernel<<<dim3(1024), dim3(128), 0, stream>>>(qkv, vt, act_b);
        gemm_bf16<1, 0, 64><<<dim3(128, 4), dim3(256), 0, stream>>>(act_b, woT, bo + i * D, nullptr, nullptr,
                                                                    h, h, nullptr, Bsz * T, D, D, gate1 + i);
        ln_bf16_kernel<<<dim3(Bsz * T / 4), dim3(256), 0, stream>>>(h, act_b, ln2_g + i * D, ln2_b + i * D);
        gemm_bf16<2, 1, 128><<<dim3(64, 16), dim3(256), 0, stream>>>(act_b, w1T, b1 + i * DFF, nullptr, nullptr,
                                                                     nullptr, mid_b, nullptr, Bsz * T, DFF, D, nullptr);
        gemm_bf16<3, 0, 64><<<dim3(128, 4), dim3(256), 0, stream>>>(mid_b, w2T, b2 + i * D, nullptr, nullptr,
                                                                    h, h, nullptr, Bsz * T, D, DFF, gate2 + i);
    }

    ln_kernel<<<dim3(Bsz * T / 4), dim3(256), 0, stream>>>(h, xn_f, fn_g, fn_b);
    pool_kernel<<<dim3(Bsz, 16), dim3(256), 0, stream>>>(xn_f, x, part);
    head_kernel<<<dim3(Bsz), dim3(64), 0, stream>>>(part, bh_g, bh_bl, ah_g, ah_bl, ch_g, ch_bl,
                                                    bh_w, bh_b2, ah_w, ah_b2, ch_w, ch_b2, out);
}

// Round 12
// 1179.206 us; speedup vs baseline: 1.1155x; 1.0025x over previous
//
#include <hip/hip_runtime.h>
#include <hip/hip_bf16.h>
#include <math.h>

// ---------------- constants ----------------
constexpr int Bsz = 4, T = 2048, D = 512, H = 8, Lnum = 6, DFF = 2048, DK = 64;
constexpr int QS2 = 1024;                       // qkv row stride (q at 0, k at 512; v goes to vt)
constexpr float K2 = 0.08838834764831845f / 1.5f;  // softmax exponent scale (folded into q)

typedef __attribute__((ext_vector_type(8))) short svec8;   // 8 bf16 (4 VGPRs)
typedef __attribute__((ext_vector_type(4))) float fvec4;   // 4 fp32 acc

__device__ __forceinline__ fvec4 mfma16(svec8 a, svec8 b, fvec4 c) {
    return __builtin_amdgcn_mfma_f32_16x16x32_bf16(a, b, c, 0, 0, 0);
}
__device__ __forceinline__ unsigned short f2b(float f) {
    unsigned int u = __float_as_uint(f);
    u += 0x7fffu + ((u >> 16) & 1u);
    return (unsigned short)(u >> 16);
}
__device__ __forceinline__ unsigned int pk2b(float a, float b) {
    __hip_bfloat162 h = __float22bfloat162_rn(float2{a, b});
    return *(unsigned int*)&h;
}
__device__ __forceinline__ float wave_red_sum(float v) {
    for (int o = 32; o > 0; o >>= 1) v += __shfl_down(v, o, 64);
    return __shfl(v, 0, 64);
}
// async global->LDS, 16B per lane; lds base must be wave-uniform (HW adds lane*16)
__device__ __forceinline__ void glds16(const unsigned short* g, unsigned short* l) {
    __builtin_amdgcn_global_load_lds(
        (const __attribute__((address_space(1))) unsigned int*)g,
        (__attribute__((address_space(3))) unsigned int*)l, 16, 0, 0);
}
// swizzled-tile fragment read: 64-wide rows, chunk kq of row r at slot kq^(r&7)
#define FRAG(buf, row, kq) (*(const svec8*)((buf) + (((row) << 6) | ((((kq) ^ ((row) & 7))) << 3))))

// ---------------- embed (fp32 h) ----------------
__global__ __launch_bounds__(64)
void embed_kernel(const float* __restrict__ x, const float* __restrict__ ip_w,
                  const float* __restrict__ ip_b, const float* __restrict__ g,
                  const float* __restrict__ bta, const float* __restrict__ pos,
                  const float* __restrict__ pad_tok, float* __restrict__ h)
{
    int row = blockIdx.x;
    int t = row & (T - 1);
    int lane = threadIdx.x;
    float xv = x[row];
    float xc = fminf(fmaxf(xv, -10.f), 10.f);
    bool pad = (xc == -1.0f);
    float pre[8];
    float s = 0.f, s2 = 0.f;
#pragma unroll
    for (int j = 0; j < 8; j++) {
        int d = j * 64 + lane;
        float p = xc * ip_w[d] + ip_b[d];
        pre[j] = p; s += p; s2 += p * p;
    }
    s = wave_red_sum(s); s2 = wave_red_sum(s2);
    float m = s * (1.f / 512.f);
    float var = s2 * (1.f / 512.f) - m * m;
    float rstd = 1.f / sqrtf(var + 1e-5f);
#pragma unroll
    for (int j = 0; j < 8; j++) {
        int d = j * 64 + lane;
        float hv = (pre[j] - m) * rstd * g[d] + bta[d] + 0.1f * pos[(size_t)t * D + d];
        if (pad) hv = pad_tok[d];
        h[(size_t)row * D + d] = hv;
    }
}

// ---------------- LayerNorm fp32 -> fp32 (final), 4 rows/block ----------------
__global__ __launch_bounds__(256)
void ln_kernel(const float* __restrict__ in, float* __restrict__ out,
               const float* __restrict__ g, const float* __restrict__ b)
{
    int row = blockIdx.x * 4 + (threadIdx.x >> 6);
    int lane = threadIdx.x & 63;
    const float* r = in + (size_t)row * D;
    float4 v0 = ((const float4*)r)[lane];
    float4 v1 = ((const float4*)r)[lane + 64];
    float s = v0.x + v0.y + v0.z + v0.w + v1.x + v1.y + v1.z + v1.w;
    float s2 = v0.x*v0.x + v0.y*v0.y + v0.z*v0.z + v0.w*v0.w
             + v1.x*v1.x + v1.y*v1.y + v1.z*v1.z + v1.w*v1.w;
    s = wave_red_sum(s); s2 = wave_red_sum(s2);
    float m = s * (1.f / 512.f);
    float var = s2 * (1.f / 512.f) - m * m;
    float rstd = 1.f / sqrtf(var + 1e-5f);
    float4 g0 = ((const float4*)g)[lane], g1 = ((const float4*)g)[lane + 64];
    float4 b0 = ((const float4*)b)[lane], b1 = ((const float4*)b)[lane + 64];
    float4 o0, o1;
    o0.x = (v0.x - m) * rstd * g0.x + b0.x; o0.y = (v0.y - m) * rstd * g0.y + b0.y;
    o0.z = (v0.z - m) * rstd * g0.z + b0.z; o0.w = (v0.w - m) * rstd * g0.w + b0.w;
    o1.x = (v1.x - m) * rstd * g1.x + b1.x; o1.y = (v1.y - m) * rstd * g1.y + b1.y;
    o1.z = (v1.z - m) * rstd * g1.z + b1.z; o1.w = (v1.w - m) * rstd * g1.w + b1.w;
    ((float4*)(out + (size_t)row * D))[lane] = o0;
    ((float4*)(out + (size_t)row * D))[lane + 64] = o1;
}

// ---------------- device LN fp32 -> bf16 helper (one wave, one row) ----------------
__device__ __forceinline__ void ln_row_bf16(const float* __restrict__ in, unsigned short* __restrict__ out,
                                            const float* __restrict__ g, const float* __restrict__ b,
                                            int row, int lane)
{
    const float* r = in + (size_t)row * D;
    float4 v0 = ((const float4*)r)[lane];
    float4 v1 = ((const float4*)r)[lane + 64];
    float s = v0.x + v0.y + v0.z + v0.w + v1.x + v1.y + v1.z + v1.w;
    float s2 = v0.x*v0.x + v0.y*v0.y + v0.z*v0.z + v0.w*v0.w
             + v1.x*v1.x + v1.y*v1.y + v1.z*v1.z + v1.w*v1.w;
    s = wave_red_sum(s); s2 = wave_red_sum(s2);
    float m = s * (1.f / 512.f);
    float var = s2 * (1.f / 512.f) - m * m;
    float rstd = 1.f / sqrtf(var + 1e-5f);
    float4 g0 = ((const float4*)g)[lane], g1 = ((const float4*)g)[lane + 64];
    float4 b0 = ((const float4*)b)[lane], b1 = ((const float4*)b)[lane + 64];
    unsigned short o0[4], o1[4];
    o0[0] = f2b((v0.x - m) * rstd * g0.x + b0.x); o0[1] = f2b((v0.y - m) * rstd * g0.y + b0.y);
    o0[2] = f2b((v0.z - m) * rstd * g0.z + b0.z); o0[3] = f2b((v0.w - m) * rstd * g0.w + b0.w);
    o1[0] = f2b((v1.x - m) * rstd * g1.x + b1.x); o1[1] = f2b((v1.y - m) * rstd * g1.y + b1.y);
    o1[2] = f2b((v1.z - m) * rstd * g1.z + b1.z); o1[3] = f2b((v1.w - m) * rstd * g1.w + b1.w);
    *(uint2*)(out + (size_t)row * D + lane * 4) = *(uint2*)o0;
    *(uint2*)(out + (size_t)row * D + 256 + lane * 4) = *(uint2*)o1;
}

__global__ __launch_bounds__(256)
void ln_bf16_kernel(const float* __restrict__ in, unsigned short* __restrict__ out,
                    const float* __restrict__ g, const float* __restrict__ b)
{
    ln_row_bf16(in, out, g, b, blockIdx.x * 4 + (threadIdx.x >> 6), threadIdx.x & 63);
}

// ---------------- fused per-layer prep: wconv (bid<3072) + ln1 (bid in [3072,5120)) ----------------
__global__ __launch_bounds__(256)
void prep_kernel(const float* __restrict__ wq, const float* __restrict__ wk,
                 const float* __restrict__ wv, const float* __restrict__ wo,
                 const float* __restrict__ w1, const float* __restrict__ w2,
                 unsigned short* __restrict__ oq, unsigned short* __restrict__ ok,
                 unsigned short* __restrict__ ov, unsigned short* __restrict__ oo,
                 unsigned short* __restrict__ o1, unsigned short* __restrict__ o2,
                 const float* __restrict__ hin, unsigned short* __restrict__ lnout,
                 const float* __restrict__ ln_g, const float* __restrict__ ln_b)
{
    __shared__ float tile[32][33];
    int bid = blockIdx.x;
    if (bid >= 3072) {
        int row = (bid - 3072) * 4 + (threadIdx.x >> 6);
        ln_row_bf16(hin, lnout, ln_g, ln_b, row, threadIdx.x & 63);
        return;
    }
    const float* in; unsigned short* out; int K, N, kt, nt;
    if (bid < 1024) {
        int sel = bid >> 8, loc = bid & 255;
        in  = sel == 0 ? wq : sel == 1 ? wk : sel == 2 ? wv : wo;
        out = sel == 0 ? oq : sel == 1 ? ok : sel == 2 ? ov : oo;
        K = 512; N = 512; kt = loc >> 4; nt = loc & 15;
    } else if (bid < 2048) {
        int loc = bid - 1024; in = w1; out = o1; K = 512; N = 2048; kt = loc >> 6; nt = loc & 63;
    } else {
        int loc = bid - 2048; in = w2; out = o2; K = 2048; N = 512; kt = loc >> 4; nt = loc & 15;
    }
    int k0 = kt * 32, n0 = nt * 32;
    int t = threadIdx.x;
    int kr = t >> 3, nc = (t & 7) * 4;
    float4 v = *(const float4*)(in + (size_t)(k0 + kr) * N + n0 + nc);
    tile[kr][nc] = v.x; tile[kr][nc + 1] = v.y; tile[kr][nc + 2] = v.z; tile[kr][nc + 3] = v.w;
    __syncthreads();
    unsigned short o[4];
#pragma unroll
    for (int i = 0; i < 4; i++) o[i] = f2b(tile[nc + i][kr]);
    *(uint2*)(out + (size_t)(n0 + kr) * K + k0 + nc) = *(uint2*)o;
}

// ---------------- bf16 MFMA GEMM, global_load_lds + BK=64 XOR swizzle ----------------
template<int EPI, int OBF, int BM>
__global__ __launch_bounds__(256)
void gemm_bf16(const unsigned short* __restrict__ A, const unsigned short* __restrict__ BT,
               const float* __restrict__ bias, const float* __restrict__ bias_b,
               const float* __restrict__ bias_c, const float* __restrict__ res,
               void* __restrict__ Cv, unsigned short* __restrict__ vtout,
               int M, int N, int K, const float* __restrict__ gate_p)
{
    constexpr int WN = (BM == 128) ? 2 : 4;
    constexpr int WSPAN = 128 / WN;
    constexpr int NT = WSPAN / 16;
    constexpr int MT = 4;
    constexpr int ACALLS = BM / 32;
    constexpr int SMEMSZ = (EPI == 0) ? 17408 : (BM * 64 + 128 * 64);
    __shared__ __align__(16) unsigned short SMEM[SMEMSZ];
    unsigned short* As = SMEM;
    unsigned short* Bs = SMEM + BM * 64;
    const int tid = threadIdx.x, w = tid >> 6, lane = tid & 63, quad = lane >> 4, ln = lane & 15;
    const int wm = w / WN, wn = w % WN;
    const int m0 = blockIdx.x * BM, n0 = blockIdx.y * 128;
    const int jg = (lane & 7) ^ ((lane >> 3) & 7);
    const int rb = w * 8 + (lane >> 3);
    const unsigned short* Agl = A + (size_t)(m0 + rb) * K + jg * 8;
    const unsigned short* Bgl = BT + (size_t)(n0 + rb) * K + jg * 8;

    fvec4 acc[MT][NT];
#pragma unroll
    for (int mt = 0; mt < MT; mt++)
#pragma unroll
        for (int nt = 0; nt < NT; nt++)
#pragma unroll
            for (int r = 0; r < 4; r++) acc[mt][nt][r] = 0.f;

    for (int k0 = 0; k0 < K; k0 += 64) {
        __syncthreads();
#pragma unroll
        for (int c = 0; c < ACALLS; c++)
            glds16(Agl + k0 + (size_t)c * 32 * K, As + c * 2048 + w * 512);
#pragma unroll
        for (int c = 0; c < 4; c++)
            glds16(Bgl + k0 + (size_t)c * 32 * K, Bs + c * 2048 + w * 512);
        __syncthreads();
#pragma unroll
        for (int kk = 0; kk < 2; kk++) {
            svec8 af[MT], bfr[NT];
#pragma unroll
            for (int mt = 0; mt < MT; mt++)
                af[mt] = FRAG(As, wm * 64 + mt * 16 + ln, kk * 4 + quad);
#pragma unroll
            for (int nt = 0; nt < NT; nt++)
                bfr[nt] = FRAG(Bs, wn * WSPAN + nt * 16 + ln, kk * 4 + quad);
#pragma unroll
            for (int mt = 0; mt < MT; mt++)
#pragma unroll
                for (int nt = 0; nt < NT; nt++)
                    acc[mt][nt] = mfma16(af[mt], bfr[nt], acc[mt][nt]);
        }
    }

    const float gate = (EPI == 1 || EPI == 3) ? gate_p[0] : 0.f;
    float bb[NT];
#pragma unroll
    for (int nt = 0; nt < NT; nt++) {
        int n = n0 + wn * WSPAN + nt * 16 + ln;
        if (EPI == 0) {
            int nseg = n >> 9;
            const float* bsel = nseg == 0 ? bias : (nseg == 1 ? bias_b : bias_c);
            bb[nt] = bsel[n - nseg * 512];
        } else {
            bb[nt] = bias[n];
        }
    }

    if (EPI == 0 && n0 >= 1024) {
        __syncthreads();
#pragma unroll
        for (int mt = 0; mt < MT; mt++) {
#pragma unroll
            for (int nt = 0; nt < NT; nt++) {
                int nl = wn * 64 + nt * 16 + ln;
                int mb = wm * 64 + mt * 16 + quad * 4;
                unsigned int lo = pk2b(acc[mt][nt][0] + bb[nt], acc[mt][nt][1] + bb[nt]);
                unsigned int hi = pk2b(acc[mt][nt][2] + bb[nt], acc[mt][nt][3] + bb[nt]);
                uint2 u; u.x = lo; u.y = hi;
                *(uint2*)(SMEM + nl * 136 + mb) = u;
            }
        }
        __syncthreads();
        int row = tid >> 1, half = (tid & 1) * 64;
        unsigned short* dst = vtout + ((size_t)((m0 >> 11) * 512 + (n0 - 1024) + row)) * T
                              + (m0 & (T - 1)) + half;
        const unsigned short* src = SMEM + row * 136 + half;
#pragma unroll
        for (int j = 0; j < 8; j++) *(uint4*)(dst + j * 8) = *(const uint4*)(src + j * 8);
        return;
    }

#pragma unroll
    for (int mt = 0; mt < MT; mt++) {
        float v[NT][4];
#pragma unroll
        for (int nt = 0; nt < NT; nt++)
#pragma unroll
            for (int r = 0; r < 4; r++) v[nt][r] = acc[mt][nt][r] + bb[nt];
        if (EPI == 0) {   // q/k: fused L2 norm; q additionally pre-scaled by K2
            const float fac = ((n0 + wn * WSPAN) < 512) ? K2 : 1.f;
#pragma unroll
            for (int r = 0; r < 4; r++) {
                float s = 0.f;
#pragma unroll
                for (int nt = 0; nt < NT; nt++) s += v[nt][r] * v[nt][r];
                s += __shfl_xor(s, 1); s += __shfl_xor(s, 2);
                s += __shfl_xor(s, 4); s += __shfl_xor(s, 8);
                float rs = fac / fmaxf(sqrtf(s), 1e-8f);
#pragma unroll
                for (int nt = 0; nt < NT; nt++) v[nt][r] *= rs;
            }
        }
#pragma unroll
        for (int nt = 0; nt < NT; nt++) {
            int n = n0 + wn * WSPAN + nt * 16 + ln;
#pragma unroll
            for (int r = 0; r < 4; r++) {
                int m = m0 + wm * 64 + mt * 16 + quad * 4 + r;
                float val = v[nt][r];
                if (EPI == 0) {
                    ((unsigned short*)Cv)[(size_t)m * QS2 + n] = f2b(val);
                } else {
                    size_t off = (size_t)m * N + n;
                    if (EPI == 1) val = res[off] + gate * 0.5f * val;
                    else if (EPI == 2) {
                        float u = val;
                        float z = 0.7978845608028654f * fmaf(0.044715f * u, u * u, u);
                        float e = __builtin_amdgcn_exp2f(z * 2.8853900817779268f);
                        float rr = __builtin_amdgcn_rcpf(e + 1.f);
                        val = u * (1.f - rr);
                    }
                    else if (EPI == 3) val = fminf(fmaxf(res[off] + gate * val, -10.f), 10.f);
                    if (OBF) ((unsigned short*)Cv)[off] = f2b(val);
                    else ((float*)Cv)[off] = val;
                }
            }
        }
    }
}

// ---------------- flash attention v3: paired qt per block, 2 waves x 32 static rows of BOTH tiles ----------------
// MA: also process tile A (s <= p); DIAG: a diagonal mask is active (A's at s==p, B's at s==nst-1;
// they never coincide since p<16<=31-p). All accumulator indexing compile-time.
template<bool MA, bool DIAG>
__device__ __forceinline__ void attn_stepP(
    unsigned short* PsA, unsigned short* PsB,
    const unsigned short* Ks, const unsigned short* Vt,
    const svec8 (&qfA)[2][2], const svec8 (&qfB)[2][2],
    fvec4 (&oA)[2][4], fvec4 (&lA)[2], fvec4 (&oB)[2][4], fvec4 (&lB)[2],
    int w, int quad, int ln)
{
    constexpr short BONE = (short)0x3F80;     // bf16 1.0
    const svec8 ONES8 = {BONE, BONE, BONE, BONE, BONE, BONE, BONE, BONE};
#pragma unroll
    for (int nt = 0; nt < 4; nt++) {
        svec8 kf0 = FRAG(Ks, nt * 16 + ln, quad);
        svec8 kf1 = FRAG(Ks, nt * 16 + ln, 4 + quad);
        const int sbase = nt * 16 + quad * 4;
#pragma unroll
        for (int qg = 0; qg < 2; qg++) {
            const int qcol = w * 32 + qg * 16 + ln;
            const int paddr = (qcol << 6) | ((((sbase >> 3) ^ (qcol & 7))) << 3) | (sbase & 7);
            {   // B tile (diag only when !MA: B's diag step has s>p)
                fvec4 z; z[0] = z[1] = z[2] = z[3] = 0.f;
                z = mfma16(kf0, qfB[qg][0], z);
                z = mfma16(kf1, qfB[qg][1], z);
                float p[4];
#pragma unroll
                for (int r = 0; r < 4; r++) {
                    float y = z[r];
                    float pv = fmaf(y, fmaf(y, 0.5f, 1.f), 1.f);   // e^y quadratic, |y|<=0.059
                    if (DIAG && !MA && (sbase + r > qcol)) pv = 0.f;
                    p[r] = pv;
                }
                uint2 u; u.x = pk2b(p[0], p[1]); u.y = pk2b(p[2], p[3]);
                *(uint2*)(PsB + paddr) = u;
            }
            if (MA) {   // A tile reuses kf0/kf1 (diag when s==p)
                fvec4 z; z[0] = z[1] = z[2] = z[3] = 0.f;
                z = mfma16(kf0, qfA[qg][0], z);
                z = mfma16(kf1, qfA[qg][1], z);
                float p[4];
#pragma unroll
                for (int r = 0; r < 4; r++) {
                    float y = z[r];
                    float pv = fmaf(y, fmaf(y, 0.5f, 1.f), 1.f);
                    if (DIAG && (sbase + r > qcol)) pv = 0.f;
                    p[r] = pv;
                }
                uint2 u; u.x = pk2b(p[0], p[1]); u.y = pk2b(p[2], p[3]);
                *(uint2*)(PsA + paddr) = u;
            }
        }
    }
#pragma unroll
    for (int ks = 0; ks < 2; ks++) {
        svec8 paB[2], paA[2];
#pragma unroll
        for (int qg = 0; qg < 2; qg++) {
            paB[qg] = FRAG(PsB, w * 32 + qg * 16 + ln, ks * 4 + quad);
            lB[qg] = mfma16(paB[qg], ONES8, lB[qg]);
            if (MA) {
                paA[qg] = FRAG(PsA, w * 32 + qg * 16 + ln, ks * 4 + quad);
                lA[qg] = mfma16(paA[qg], ONES8, lA[qg]);
            }
        }
#pragma unroll
        for (int dkn = 0; dkn < 4; dkn++) {
            svec8 vf = FRAG(Vt, dkn * 16 + ln, ks * 4 + quad);
#pragma unroll
            for (int qg = 0; qg < 2; qg++) {
                oB[qg][dkn] = mfma16(paB[qg], vf, oB[qg][dkn]);
                if (MA) oA[qg][dkn] = mfma16(paA[qg], vf, oA[qg][dkn]);
            }
        }
    }
}

__global__ __launch_bounds__(128)
void attn_kernel(const unsigned short* __restrict__ qkv, const unsigned short* __restrict__ vt,
                 unsigned short* __restrict__ o)
{
    // 48 KB LDS; 512 blocks x 33 identical steps (perfect balance); K/V shared by both tiles.
    __shared__ __align__(16) unsigned short K0[4096], V0[4096], K1[4096], V1[4096];
    __shared__ __align__(16) unsigned short PsA[4096], PsB[4096];
    // R8 decode: 4 heads per XCD (FETCH win), pair (p, 31-p) per block
    const int fid = blockIdx.x;
    const int xcd = fid & 7, slot = fid >> 3;
    const int bh = xcd * 4 + (slot & 3);
    const int p = slot >> 2;
    const int b = bh >> 3, hh = bh & 7;
    const int qtA = p, qtB = 31 - p, nst = 32 - p;
    const int tid = threadIdx.x, w = tid >> 6, lane = tid & 63, quad = lane >> 4, ln = lane & 15;
    const int jgz = (lane & 7) ^ (lane >> 3);

    // Q fragments for this wave's 32 rows of both tiles, straight from global
    svec8 qfA[2][2], qfB[2][2];
#pragma unroll
    for (int qg = 0; qg < 2; qg++) {
        const unsigned short* qpA = qkv + ((size_t)(b * T + qtA * 64 + w * 32 + qg * 16 + ln)) * QS2 + hh * 64;
        const unsigned short* qpB = qkv + ((size_t)(b * T + qtB * 64 + w * 32 + qg * 16 + ln)) * QS2 + hh * 64;
        qfA[qg][0] = *(const svec8*)(qpA + quad * 8);
        qfA[qg][1] = *(const svec8*)(qpA + 32 + quad * 8);
        qfB[qg][0] = *(const svec8*)(qpB + quad * 8);
        qfB[qg][1] = *(const svec8*)(qpB + 32 + quad * 8);
    }

    // staging bases: wave w stages rows {w*8+(lane>>3)} + 16*cc (union of 2 waves = all 64 rows)
    const unsigned short* kbase = qkv + ((size_t)(b * T) + w * 8 + (lane >> 3)) * QS2 + 512 + hh * 64 + jgz * 8;
    const unsigned short* vbase = vt + ((size_t)(bh * 64) + w * 8 + (lane >> 3)) * T + jgz * 8;
    const int ldsoff = w * 8 * 64;

    fvec4 oA[2][4], oB[2][4], lA[2], lB[2];
#pragma unroll
    for (int qg = 0; qg < 2; qg++) {
#pragma unroll
        for (int r = 0; r < 4; r++) { lA[qg][r] = 0.f; lB[qg][r] = 0.f; }
#pragma unroll
        for (int dkn = 0; dkn < 4; dkn++)
#pragma unroll
            for (int r = 0; r < 4; r++) { oA[qg][dkn][r] = 0.f; oB[qg][dkn][r] = 0.f; }
    }

    const int Nph = (nst + 1) >> 1;
    for (int ph = 0; ph < Nph; ph++) {
        const int s0 = 2 * ph, s1 = 2 * ph + 1;
        __syncthreads();   // previous phase's reads of K/V done
#pragma unroll
        for (int cc = 0; cc < 4; cc++) {
            glds16(kbase + ((size_t)(s0 * 64) + cc * 16) * QS2, K0 + cc * 1024 + ldsoff);
            glds16(vbase + (size_t)(cc * 16) * T + s0 * 64, V0 + cc * 1024 + ldsoff);
        }
        if (s1 < nst) {
#pragma unroll
            for (int cc = 0; cc < 4; cc++) {
                glds16(kbase + ((size_t)(s1 * 64) + cc * 16) * QS2, K1 + cc * 1024 + ldsoff);
                glds16(vbase + (size_t)(cc * 16) * T + s1 * 64, V1 + cc * 1024 + ldsoff);
            }
        }
        __syncthreads();   // staged data visible
        {   // step s0
            if (s0 <= p) {
                if (s0 == p) attn_stepP<true , true >(PsA, PsB, K0, V0, qfA, qfB, oA, lA, oB, lB, w, quad, ln);
                else         attn_stepP<true , false>(PsA, PsB, K0, V0, qfA, qfB, oA, lA, oB, lB, w, quad, ln);
            } else {
                if (s0 == nst - 1) attn_stepP<false, true >(PsA, PsB, K0, V0, qfA, qfB, oA, lA, oB, lB, w, quad, ln);
                else               attn_stepP<false, false>(PsA, PsB, K0, V0, qfA, qfB, oA, lA, oB, lB, w, quad, ln);
            }
        }
        if (s1 < nst) {
            if (s1 <= p) {
                if (s1 == p) attn_stepP<true , true >(PsA, PsB, K1, V1, qfA, qfB, oA, lA, oB, lB, w, quad, ln);
                else         attn_stepP<true , false>(PsA, PsB, K1, V1, qfA, qfB, oA, lA, oB, lB, w, quad, ln);
            } else {
                if (s1 == nst - 1) attn_stepP<false, true >(PsA, PsB, K1, V1, qfA, qfB, oA, lA, oB, lB, w, quad, ln);
                else               attn_stepP<false, false>(PsA, PsB, K1, V1, qfA, qfB, oA, lA, oB, lB, w, quad, ln);
            }
        }
    }

    // direct epilogue — wave owns its 32 rows of both tiles (static indexing)
    unsigned short* ogA = o + (size_t)(b * T + qtA * 64 + w * 32 + quad * 4) * D + hh * 64;
    unsigned short* ogB = o + (size_t)(b * T + qtB * 64 + w * 32 + quad * 4) * D + hh * 64;
#pragma unroll
    for (int qg = 0; qg < 2; qg++) {
#pragma unroll
        for (int r = 0; r < 4; r++) {
            float ia = 1.f / lA[qg][r];
            float ib = 1.f / lB[qg][r];
#pragma unroll
            for (int dkn = 0; dkn < 4; dkn++) {
                ogA[(size_t)(qg * 16 + r) * D + dkn * 16 + ln] = f2b(oA[qg][dkn][r] * ia);
                ogB[(size_t)(qg * 16 + r) * D + dkn * 16 + ln] = f2b(oB[qg][dkn][r] * ib);
            }
        }
    }
}

// ---------------- masked-mean pool partials ----------------
__global__ __launch_bounds__(256)
void pool_kernel(const float* __restrict__ hn, const float* __restrict__ x, float* __restrict__ part)
{
    int b = blockIdx.x, ch = blockIdx.y, tid = threadIdx.x;
    int t0 = ch * 128;
    float s0 = 0.f, s1 = 0.f, cnt = 0.f;
    for (int tt = 0; tt < 128; tt++) {
        int t = t0 + tt;
        float xv = x[b * T + t];
        float m = (xv == -1.0f) ? 0.f : 1.f;
        cnt += m;
        const float* r = hn + ((size_t)(b * T + t)) * D;
        s0 += r[tid] * m;
        s1 += r[tid + 256] * m;
    }
    float* pr = part + (size_t)(b * 16 + ch) * 513;
    pr[tid] = s0; pr[tid + 256] = s1;
    if (tid == 0) pr[512] = cnt;
}

// ---------------- heads ----------------
__global__ __launch_bounds__(64)
void head_kernel(const float* __restrict__ part,
                 const float* __restrict__ bh_g, const float* __restrict__ bh_bl,
                 const float* __restrict__ ah_g, const float* __restrict__ ah_bl,
                 const float* __restrict__ ch_g, const float* __restrict__ ch_bl,
                 const float* __restrict__ bh_w, const float* __restrict__ bh_b2,
                 const float* __restrict__ ah_w, const float* __restrict__ ah_b2,
                 const float* __restrict__ ch_w, const float* __restrict__ ch_b2,
                 float* __restrict__ out)
{
    int b = blockIdx.x, lane = threadIdx.x;
    float cnt = 0.f;
    for (int c = 0; c < 16; c++) cnt += part[(size_t)(b * 16 + c) * 513 + 512];
    float denom = fmaxf(cnt, 1.f);
    float md[8];
    float s = 0.f, s2 = 0.f;
#pragma unroll
    for (int j = 0; j < 8; j++) {
        int d = j * 64 + lane;
        float acc = 0.f;
        for (int c = 0; c < 16; c++) acc += part[(size_t)(b * 16 + c) * 513 + d];
        md[j] = acc / denom;
        s += md[j]; s2 += md[j] * md[j];
    }
    s = wave_red_sum(s); s2 = wave_red_sum(s2);
    float mu = s * (1.f / 512.f);
    float var = s2 * (1.f / 512.f) - mu * mu;
    float rstd = 1.f / sqrtf(var + 1e-5f);
    float a0 = 0.f, a1 = 0.f, a2 = 0.f, a3 = 0.f;
#pragma unroll
    for (int j = 0; j < 8; j++) {
        int d = j * 64 + lane;
        float z = (md[j] - mu) * rstd;
        float zb = z * bh_g[d] + bh_bl[d];
        a0 += zb * bh_w[d * 2 + 0];
        a1 += zb * bh_w[d * 2 + 1];
        a2 += (z * ah_g[d] + ah_bl[d]) * ah_w[d];
        a3 += (z * ch_g[d] + ch_bl[d]) * ch_w[d];
    }
    a0 = wave_red_sum(a0); a1 = wave_red_sum(a1);
    a2 = wave_red_sum(a2); a3 = wave_red_sum(a3);
    if (lane == 0) {
        out[b * 4 + 0] = a0 + bh_b2[0];
        out[b * 4 + 1] = a1 + bh_b2[1];
        out[b * 4 + 2] = a2 + ah_b2[0];
        float t3 = a3 + ch_b2[0];
        out[b * 4 + 3] = 1.f / (1.f + expf(-t3));
    }
}

// ---------------- launch ----------------
extern "C" void kernel_launch(void* const* d_in, const int* in_sizes, int n_in,
                              void* d_out, int out_size, void* d_ws, size_t ws_size,
                              hipStream_t stream)
{
    const float* x      = (const float*)d_in[0];
    const float* ip_w   = (const float*)d_in[1];
    const float* ip_b   = (const float*)d_in[2];
    const float* ip_ln_g= (const float*)d_in[3];
    const float* ip_ln_b= (const float*)d_in[4];
    const float* pos    = (const float*)d_in[5];
    const float* pad_tok= (const float*)d_in[6];
    const float* Wq = (const float*)d_in[7];  const float* bq = (const float*)d_in[8];
    const float* Wk = (const float*)d_in[9];  const float* bk = (const float*)d_in[10];
    const float* Wv = (const float*)d_in[11]; const float* bv = (const float*)d_in[12];
    const float* Wo = (const float*)d_in[13]; const float* bo = (const float*)d_in[14];
    const float* ln1_g = (const float*)d_in[15]; const float* ln1_b = (const float*)d_in[16];
    const float* ln2_g = (const float*)d_in[17]; const float* ln2_b = (const float*)d_in[18];
    const float* W1 = (const float*)d_in[19]; const float* b1 = (const float*)d_in[20];
    const float* W2 = (const float*)d_in[21]; const float* b2 = (const float*)d_in[22];
    const float* gate1 = (const float*)d_in[23]; const float* gate2 = (const float*)d_in[24];
    const float* fn_g = (const float*)d_in[25]; const float* fn_b = (const float*)d_in[26];
    const float* bh_g  = (const float*)d_in[27]; const float* bh_bl = (const float*)d_in[28];
    const float* ah_g  = (const float*)d_in[29]; const float* ah_bl = (const float*)d_in[30];
    const float* ch_g  = (const float*)d_in[31]; const float* ch_bl = (const float*)d_in[32];
    const float* bh_w  = (const float*)d_in[33]; const float* bh_b2 = (const float*)d_in[34];
    const float* ah_w  = (const float*)d_in[35]; const float* ah_b2 = (const float*)d_in[36];
    const float* ch_w  = (const float*)d_in[37]; const float* ch_b2 = (const float*)d_in[38];

    char* ws = (char*)d_ws;
    float*          h     = (float*)ws;                       // 16 MB fp32 [8192][512]
    unsigned short* act_b = (unsigned short*)(ws + 16777216); // 8 MB bf16 [8192][512]
    unsigned short* qkv   = (unsigned short*)(ws + 25165824); // 16 MB bf16 [8192][1024] (q|k)
    unsigned short* mid_b = (unsigned short*)(ws + 41943040); // 32 MB bf16 [8192][2048]
    float*          xn_f  = (float*)(ws + 41943040);          // 16 MB alias (final LN only)
    unsigned short* wT    = (unsigned short*)(ws + 75497472); // 6 MB per-layer transposed weights
    unsigned short* vt    = (unsigned short*)(ws + 81788928); // 8 MB bf16 [4*512][2048]
    float*          part  = (float*)(ws + 90177536);
    float*          out   = (float*)d_out;

    unsigned short* wqT = wT;             // [1536][512] (q,k,v contiguous)
    unsigned short* wkT = wT + 262144;
    unsigned short* wvT = wT + 524288;
    unsigned short* woT = wT + 786432;
    unsigned short* w1T = wT + 1048576;   // [2048][512]
    unsigned short* w2T = wT + 2097152;   // [512][2048]

    embed_kernel<<<dim3(Bsz * T), dim3(64), 0, stream>>>(x, ip_w, ip_b, ip_ln_g, ip_ln_b, pos, pad_tok, h);

    for (int i = 0; i < Lnum; i++) {
        const size_t dd = (size_t)i * D * D;
        const size_t df = (size_t)i * D * DFF;
        prep_kernel<<<dim3(5120), dim3(256), 0, stream>>>(Wq + dd, Wk + dd, Wv + dd, Wo + dd,
                                                          W1 + df, W2 + df,
                                                          wqT, wkT, wvT, woT, w1T, w2T,
                                                          h, act_b, ln1_g + i * D, ln1_b + i * D);
        gemm_bf16<0, 1, 128><<<dim3(64, 12), dim3(256), 0, stream>>>(act_b, wqT, bq + i * D, bk + i * D, bv + i * D,
                                                                     nullptr, qkv, vt, Bsz * T, 1536, D, nullptr);
        attn_kernel<<<dim3(512), dim3(128), 0, stream>>>(qkv, vt, act_b);
        gemm_bf16<1, 0, 64><<<dim3(128, 4), dim3(256), 0, stream>>>(act_b, woT, bo + i * D, nullptr, nullptr,
                                                                    h, h, nullptr, Bsz * T, D, D, gate1 + i);
        ln_bf16_kernel<<<dim3(Bsz * T / 4), dim3(256), 0, stream>>>(h, act_b, ln2_g + i * D, ln2_b + i * D);
        gemm_bf16<2, 1, 128><<<dim3(64, 16), dim3(256), 0, stream>>>(act_b, w1T, b1 + i * DFF, nullptr, nullptr,
                                                                     nullptr, mid_b, nullptr, Bsz * T, DFF, D, nullptr);
        gemm_bf16<3, 0, 64><<<dim3(128, 4), dim3(256), 0, stream>>>(mid_b, w2T, b2 + i * D, nullptr, nullptr,
                                                                    h, h, nullptr, Bsz * T, D, DFF, gate2 + i);
    }

    ln_kernel<<<dim3(Bsz * T / 4), dim3(256), 0, stream>>>(h, xn_f, fn_g, fn_b);
    pool_kernel<<<dim3(Bsz, 16), dim3(256), 0, stream>>>(xn_f, x, part);
    head_kernel<<<dim3(Bsz), dim3(64), 0, stream>>>(part, bh_g, bh_bl, ah_g, ah_bl, ch_g, ch_bl,
                                                    bh_w, bh_b2, ah_w, ah_b2, ch_w, ch_b2, out);
}